// Round 1
// baseline (929.529 us; speedup 1.0000x reference)
//
#include <hip/hip_runtime.h>
#include <hip/hip_bf16.h>
#include <math.h>

// ---------------------------------------------------------------------------
// Seq2Seq: enc GRU (T=50) + tag GRU (T=20) -> proj -> dec GRU (T=40)
//          -> logits GEMM (1280x50003, K=256, bf16 MFMA) -> LSE -> NLL loss
//
// Design:
//  * gi = x @ Wih^T + bih precomputed for all timesteps (tiled f32 GEMM,
//    embedding gather fused, relu for decoder inputs).
//  * GRU scan: one persistent block per batch element (recurrence is
//    independent per batch row) -> no grid sync. h in LDS (double buffered).
//    Whh transposed to k4-interleaved layout [k/4][768][4] so the inner loop
//    does coalesced float4 weight loads + LDS-broadcast float4 h reads.
//  * logits GEMM: bf16 MFMA 16x16x32, 64x64 tile, K=256 in one LDS load,
//    XOR-swizzled LDS (2-way max conflicts), XCD-aware block swizzle,
//    epilogue writes f32 logits to d_out and per-row-tile logsumexp
//    partials (max, sumexp) to ws.
//  * lse reduce kernel + loss kernel produce d_out[0], d_out[1].
// ---------------------------------------------------------------------------

#define H 256
#define H3 768
#define NBATCH 32
#define TIN 50
#define TTGT 40
#define TTAG 20
#define VSZ 50003
#define VP 50048          // padded to 64
#define NT 782            // VP / 64
#define MT 1280           // TTGT * NBATCH

typedef float f32x4 __attribute__((ext_vector_type(4)));
typedef short short8 __attribute__((ext_vector_type(8)));

__device__ __forceinline__ float dot4(float4 a, float4 b) {
    return a.x * b.x + a.y * b.y + a.z * b.z + a.w * b.w;
}

// ---------------- weight transpose: src[N][K] -> dst[(k/4)][N][4] ----------
__global__ void k_transpose(const float* s0, const float* s1, const float* s2,
                            const float* s3, const float* s4, const float* s5,
                            const float* s6, float* d0, float* d1, float* d2,
                            float* d3, float* d4, float* d5, float* d6) {
    int which = blockIdx.y;
    const float* s;
    float* d;
    int N, K;
    switch (which) {
        case 0: s = s0; d = d0; N = H3; K = H; break;
        case 1: s = s1; d = d1; N = H3; K = H; break;
        case 2: s = s2; d = d2; N = H3; K = H; break;
        case 3: s = s3; d = d3; N = H3; K = H; break;
        case 4: s = s4; d = d4; N = H3; K = H; break;
        case 5: s = s5; d = d5; N = H3; K = H; break;
        default: s = s6; d = d6; N = H; K = 2 * H; break;
    }
    int n = blockIdx.x;
    if (n >= N) return;
    for (int k = threadIdx.x; k < K; k += 256)
        d[(size_t)(k >> 2) * (N * 4) + n * 4 + (k & 3)] = s[(size_t)n * K + k];
}

// ---------------- out_W f32 -> bf16 padded [VP][H] -------------------------
__global__ void k_cvt_outw(const float* W, __hip_bfloat16* out) {
    int i4 = (blockIdx.x * 256 + threadIdx.x) * 4;
    if (i4 >= VP * H) return;
    int row = i4 >> 8;
    float4 v;
    if (row < VSZ) v = *(const float4*)(W + i4);
    else v = make_float4(0.f, 0.f, 0.f, 0.f);
    out[i4 + 0] = __float2bfloat16(v.x);
    out[i4 + 1] = __float2bfloat16(v.y);
    out[i4 + 2] = __float2bfloat16(v.z);
    out[i4 + 3] = __float2bfloat16(v.w);
}

// ---------------- gi = emb[toks] @ Wih^T + bih -----------------------------
// grid (T, 3 gates), block 256.  mode: 0 = plain, 2 = decoder (BOS shift + relu)
__global__ __launch_bounds__(256) void k_gi(const int* toks, int mode,
                                            const float* emb, const float* W4,
                                            const float* bih, float* gi) {
    __shared__ float x[NBATCH][H];
    int t = blockIdx.x, g = blockIdx.y, tid = threadIdx.x;
    for (int b = 0; b < NBATCH; ++b) {
        int tok;
        if (mode == 2) tok = (t == 0) ? 1 : toks[(t - 1) * NBATCH + b];
        else tok = toks[t * NBATCH + b];
        float v = emb[(size_t)tok * H + tid];
        if (mode == 2) v = fmaxf(v, 0.0f);
        x[b][tid] = v;
    }
    __syncthreads();
    int nb_ = tid & 63, mg = tid >> 6;
    float acc[4][8];
#pragma unroll
    for (int j = 0; j < 4; ++j)
#pragma unroll
        for (int mi = 0; mi < 8; ++mi) acc[j][mi] = 0.f;

    for (int k4 = 0; k4 < 64; ++k4) {
        const float4* wrow = (const float4*)(W4 + (size_t)k4 * 3072);
        float4 w0 = wrow[g * 256 + nb_];
        float4 w1 = wrow[g * 256 + nb_ + 64];
        float4 w2 = wrow[g * 256 + nb_ + 128];
        float4 w3 = wrow[g * 256 + nb_ + 192];
#pragma unroll
        for (int mi = 0; mi < 8; ++mi) {
            float4 xv = *(const float4*)&x[mg * 8 + mi][k4 * 4];
            acc[0][mi] += dot4(xv, w0);
            acc[1][mi] += dot4(xv, w1);
            acc[2][mi] += dot4(xv, w2);
            acc[3][mi] += dot4(xv, w3);
        }
    }
#pragma unroll
    for (int j = 0; j < 4; ++j) {
        int n = g * 256 + nb_ + j * 64;
        float bv = bih[n];
#pragma unroll
        for (int mi = 0; mi < 8; ++mi) {
            int m = t * NBATCH + mg * 8 + mi;
            gi[(size_t)m * H3 + n] = acc[j][mi] + bv;
        }
    }
}

// ---------------- GRU scan: one block per batch element --------------------
// two parameter sets so enc+tag share one launch (blocks [0,nset1) = set1)
__global__ __launch_bounds__(256) void k_gru(
    int nset1, const float* gi1, const float* W1, const float* bhh1,
    const float* h01, float* hT1, __hip_bfloat16* out1, int T1,
    const float* gi2, const float* W2, const float* bhh2, const float* h02,
    float* hT2, __hip_bfloat16* out2, int T2) {
    __shared__ float hbuf[2][H];
    int blk = blockIdx.x, tid = threadIdx.x;
    const float *gi, *W4, *bhh, *h0;
    float* hT;
    __hip_bfloat16* out;
    int T, b;
    if (blk < nset1) {
        gi = gi1; W4 = W1; bhh = bhh1; h0 = h01; hT = hT1; out = out1; T = T1; b = blk;
    } else {
        gi = gi2; W4 = W2; bhh = bhh2; h0 = h02; hT = hT2; out = out2; T = T2; b = blk - nset1;
    }
    hbuf[0][tid] = h0 ? h0[b * H + tid] : 0.0f;
    __syncthreads();
    float br = bhh[tid], bz = bhh[H + tid], bn = bhh[2 * H + tid];
    for (int t = 0; t < T; ++t) {
        const float* git = gi + (size_t)(t * NBATCH + b) * H3;
        float gr = git[tid], gz = git[H + tid], gn = git[2 * H + tid];
        float ar = br, az = bz, an = bn;
        const float* hc = hbuf[t & 1];
#pragma unroll 4
        for (int k4 = 0; k4 < 64; ++k4) {
            float4 hv = *(const float4*)&hc[k4 * 4];
            const float4* wrow = (const float4*)(W4 + (size_t)k4 * 3072);
            float4 wr = wrow[tid];
            float4 wz = wrow[H + tid];
            float4 wn = wrow[2 * H + tid];
            ar += dot4(hv, wr);
            az += dot4(hv, wz);
            an += dot4(hv, wn);
        }
        float r = 1.0f / (1.0f + expf(-(gr + ar)));
        float z = 1.0f / (1.0f + expf(-(gz + az)));
        float nn = tanhf(gn + r * an);
        float hn = (1.0f - z) * nn + z * hc[tid];
        if (out) out[(size_t)(t * NBATCH + b) * H + tid] = __float2bfloat16(hn);
        hbuf[(t & 1) ^ 1][tid] = hn;
        __syncthreads();
    }
    if (hT) hT[b * H + tid] = hbuf[T & 1][tid];
}

// ---------------- merged = concat(tag_h, enc_h) @ proj_W^T + proj_b --------
__global__ void k_proj(const float* tag_h, const float* enc_h,
                       const float* W4p, const float* pb, float* merged) {
    __shared__ float c[2 * H];
    int b = blockIdx.x, tid = threadIdx.x;
    c[tid] = tag_h[b * H + tid];
    c[H + tid] = enc_h[b * H + tid];
    __syncthreads();
    float acc = 0.f;
#pragma unroll 4
    for (int k4 = 0; k4 < 128; ++k4) {
        float4 cv = *(const float4*)&c[k4 * 4];
        float4 wv = ((const float4*)(W4p + (size_t)k4 * 1024))[tid];
        acc += dot4(cv, wv);
    }
    merged[b * H + tid] = acc + pb[tid];
}

// ---------------- logits GEMM: C[1280][50003] = A @ Bw^T + bias ------------
// A: bf16 [1280][256], Bw: bf16 [VP][256]. 64x64 tile, K=256, bf16 MFMA.
__global__ __launch_bounds__(256) void k_logits(const __hip_bfloat16* A,
                                                const __hip_bfloat16* Bw,
                                                const float* bias, float* dout,
                                                float* pmax, float* psum) {
    __shared__ uint4 smem[4096];  // 32KB A-tile + 32KB B-tile
    int bid = blockIdx.x;
    // XCD-aware bijective swizzle: 15640 = 8 * 1955
    int wg = (bid & 7) * 1955 + (bid >> 3);
    int nblk = wg / 20, mblk = wg % 20;  // N-major: 20 M-tiles share a B-tile
    int m0 = mblk * 64, n0 = nblk * 64;
    int tid = threadIdx.x;
    const uint4* Ag = (const uint4*)(A + (size_t)m0 * H);
    const uint4* Bg = (const uint4*)(Bw + (size_t)n0 * H);
#pragma unroll
    for (int i = 0; i < 8; ++i) {
        int c = tid + i * 256;
        int r = c >> 5, g = c & 31;
        smem[(r << 5) | (g ^ (r & 7))] = Ag[c];
    }
#pragma unroll
    for (int i = 0; i < 8; ++i) {
        int c = tid + i * 256;
        int r = c >> 5, g = c & 31;
        smem[2048 + ((r << 5) | (g ^ (r & 7)))] = Bg[c];
    }
    __syncthreads();
    int wave = tid >> 6, lane = tid & 63, lr = lane & 15, lg = lane >> 4;
    f32x4 acc[4];
#pragma unroll
    for (int ns = 0; ns < 4; ++ns) acc[ns] = (f32x4){0.f, 0.f, 0.f, 0.f};
    const short8* L = (const short8*)smem;
    int ra = wave * 16 + lr;
#pragma unroll
    for (int ks = 0; ks < 8; ++ks) {
        int ga = ks * 4 + lg;
        short8 av = L[(ra << 5) | (ga ^ (ra & 7))];
#pragma unroll
        for (int ns = 0; ns < 4; ++ns) {
            int rb = ns * 16 + lr;
            short8 bv = L[2048 + ((rb << 5) | (ga ^ (rb & 7)))];
            acc[ns] = __builtin_amdgcn_mfma_f32_16x16x32_bf16(av, bv, acc[ns], 0, 0, 0);
        }
    }
    // epilogue: bias + store f32 logits + per-row LSE partials for this tile
    float biasv[4];
    bool valid[4];
    int nn[4];
#pragma unroll
    for (int ns = 0; ns < 4; ++ns) {
        int n = n0 + ns * 16 + lr;
        nn[ns] = n;
        valid[ns] = (n < VSZ);
        biasv[ns] = valid[ns] ? bias[n] : 0.f;
    }
#pragma unroll
    for (int reg = 0; reg < 4; ++reg) {
        int m = m0 + wave * 16 + lg * 4 + reg;
        float v[4];
        float rm = -INFINITY;
#pragma unroll
        for (int ns = 0; ns < 4; ++ns) {
            v[ns] = acc[ns][reg] + biasv[ns];
            if (valid[ns]) {
                dout[2 + (size_t)m * VSZ + nn[ns]] = v[ns];
                rm = fmaxf(rm, v[ns]);
            }
        }
        for (int off = 1; off < 16; off <<= 1) rm = fmaxf(rm, __shfl_xor(rm, off));
        float se = 0.f;
#pragma unroll
        for (int ns = 0; ns < 4; ++ns)
            if (valid[ns]) se += expf(v[ns] - rm);
        for (int off = 1; off < 16; off <<= 1) se += __shfl_xor(se, off);
        if (lr == 0) {
            pmax[(size_t)m * NT + nblk] = rm;
            psum[(size_t)m * NT + nblk] = se;
        }
    }
}

// ---------------- per-row logsumexp from tile partials ---------------------
__global__ void k_lse(const float* pmax, const float* psum, float* lse) {
    int m = blockIdx.x, tid = threadIdx.x;
    __shared__ float sm[4];
    float lm = -INFINITY;
    for (int i = tid; i < NT; i += 256) lm = fmaxf(lm, pmax[(size_t)m * NT + i]);
    for (int off = 1; off < 64; off <<= 1) lm = fmaxf(lm, __shfl_xor(lm, off));
    if ((tid & 63) == 0) sm[tid >> 6] = lm;
    __syncthreads();
    float M = fmaxf(fmaxf(sm[0], sm[1]), fmaxf(sm[2], sm[3]));
    __syncthreads();
    float s = 0.f;
    for (int i = tid; i < NT; i += 256)
        s += psum[(size_t)m * NT + i] * expf(pmax[(size_t)m * NT + i] - M);
    for (int off = 1; off < 64; off <<= 1) s += __shfl_xor(s, off);
    if ((tid & 63) == 0) sm[tid >> 6] = s;
    __syncthreads();
    if (tid == 0) lse[m] = M + logf(sm[0] + sm[1] + sm[2] + sm[3]);
}

// ---------------- final NLL loss -------------------------------------------
__global__ void k_loss(const float* lse, const int* tgt, float* dout) {
    int tid = threadIdx.x;
    __shared__ float sm[4];
    float s = 0.f;
    for (int m = tid; m < MT; m += 256) {
        int tg = tgt[m];
        s += lse[m] - dout[2 + (size_t)m * VSZ + tg];
    }
    for (int off = 1; off < 64; off <<= 1) s += __shfl_xor(s, off);
    if ((tid & 63) == 0) sm[tid >> 6] = s;
    __syncthreads();
    if (tid == 0) {
        float total = sm[0] + sm[1] + sm[2] + sm[3];
        dout[0] = total / 32.0f;    // sum over t of mean over batch
        dout[1] = total / 1280.0f;  // / T_tgt
    }
}

// ---------------------------------------------------------------------------
extern "C" void kernel_launch(void* const* d_in, const int* in_sizes, int n_in,
                              void* d_out, int out_size, void* d_ws,
                              size_t ws_size, hipStream_t stream) {
    const int* input_tensor = (const int*)d_in[0];
    const int* target_tensor = (const int*)d_in[1];
    const int* tag_tensor = (const int*)d_in[2];
    const float* enc_emb = (const float*)d_in[3];
    const float* enc_Wih = (const float*)d_in[4];
    const float* enc_Whh = (const float*)d_in[5];
    const float* enc_bih = (const float*)d_in[6];
    const float* enc_bhh = (const float*)d_in[7];
    const float* tag_emb = (const float*)d_in[8];
    const float* tag_Wih = (const float*)d_in[9];
    const float* tag_Whh = (const float*)d_in[10];
    const float* tag_bih = (const float*)d_in[11];
    const float* tag_bhh = (const float*)d_in[12];
    const float* proj_W = (const float*)d_in[13];
    const float* proj_b = (const float*)d_in[14];
    const float* dec_Wih = (const float*)d_in[15];
    const float* dec_Whh = (const float*)d_in[16];
    const float* dec_bih = (const float*)d_in[17];
    const float* dec_bhh = (const float*)d_in[18];
    const float* out_W = (const float*)d_in[19];
    const float* out_b = (const float*)d_in[20];

    float* ws = (float*)d_ws;
    char* wsb = (char*)d_ws;
    // float-offset layout
    float* W4_enc_ih = ws + 0;
    float* W4_enc_hh = ws + 196608;
    float* W4_tag_ih = ws + 393216;
    float* W4_tag_hh = ws + 589824;
    float* W4_dec_ih = ws + 786432;
    float* W4_dec_hh = ws + 983040;
    float* W4_proj   = ws + 1179648;
    float* gi_enc    = ws + 1310720;
    float* gi_tag    = ws + 2539520;
    float* gi_dec    = ws + 3031040;
    float* enc_h     = ws + 4014080;
    float* tag_h     = ws + 4022272;
    float* merged    = ws + 4030464;
    float* lse       = ws + 4038656;
    __hip_bfloat16* decA  = (__hip_bfloat16*)(wsb + 16159744);
    __hip_bfloat16* outWb = (__hip_bfloat16*)(wsb + 16815104);
    float* pmax = (float*)(wsb + 42439680);
    float* psum = (float*)(wsb + 46443520);

    float* dout = (float*)d_out;

    // 1) weight transposes (6 GRU mats + proj)
    k_transpose<<<dim3(768, 7), 256, 0, stream>>>(
        enc_Wih, enc_Whh, tag_Wih, tag_Whh, dec_Wih, dec_Whh, proj_W,
        W4_enc_ih, W4_enc_hh, W4_tag_ih, W4_tag_hh, W4_dec_ih, W4_dec_hh,
        W4_proj);

    // 2) out_W -> bf16 padded
    k_cvt_outw<<<(VP * H / 4 + 255) / 256, 256, 0, stream>>>(out_W, outWb);

    // 3) gi precompute for all three GRUs
    k_gi<<<dim3(TIN, 3), 256, 0, stream>>>(input_tensor, 0, enc_emb, W4_enc_ih,
                                           enc_bih, gi_enc);
    k_gi<<<dim3(TTAG, 3), 256, 0, stream>>>(tag_tensor, 0, tag_emb, W4_tag_ih,
                                            tag_bih, gi_tag);
    k_gi<<<dim3(TTGT, 3), 256, 0, stream>>>(target_tensor, 2, enc_emb,
                                            W4_dec_ih, dec_bih, gi_dec);

    // 4) encoder + tag GRU scans (one launch, 64 blocks)
    k_gru<<<64, 256, 0, stream>>>(32, gi_enc, W4_enc_hh, enc_bhh, nullptr,
                                  enc_h, nullptr, TIN, gi_tag, W4_tag_hh,
                                  tag_bhh, nullptr, tag_h, nullptr, TTAG);

    // 5) proj -> merged
    k_proj<<<32, 256, 0, stream>>>(tag_h, enc_h, W4_proj, proj_b, merged);

    // 6) decoder GRU scan (writes bf16 A matrix)
    k_gru<<<32, 256, 0, stream>>>(32, gi_dec, W4_dec_hh, dec_bhh, merged,
                                  nullptr, decA, TTGT, nullptr, nullptr,
                                  nullptr, nullptr, nullptr, nullptr, 0);

    // 7) logits GEMM + LSE partials   (grid = 782 * 20 = 15640)
    k_logits<<<NT * 20, 256, 0, stream>>>(decA, outWb, out_b, dout, pmax, psum);

    // 8) per-row logsumexp
    k_lse<<<MT, 256, 0, stream>>>(pmax, psum, lse);

    // 9) loss scalars
    k_loss<<<1, 256, 0, stream>>>(lse, target_tensor, dout);
}

// Round 2
// 848.227 us; speedup vs baseline: 1.0958x; 1.0958x over previous
//
#include <hip/hip_runtime.h>
#include <hip/hip_bf16.h>
#include <math.h>

// ---------------------------------------------------------------------------
// Seq2Seq: enc GRU (T=50) + tag GRU (T=20) -> proj -> dec GRU (T=40)
//          -> logits GEMM (1280x50003, K=256, bf16 MFMA) -> LSE -> NLL loss
//
// Round 2: GRU scans rewritten as persistent multi-block kernels with a
// device-scope grid barrier per timestep.  16 blocks per GRU; each block
// caches its 48-row slice of Whh (bf16) in LDS once; h element lives in a
// register per thread (f32 master); recurrent matmul h@Whh^T done with
// bf16 MFMA 16x16x32 (batch M=32, gates N=48/block, K=256).
// enc and tag scans run concurrently as two block-groups in one launch.
// ---------------------------------------------------------------------------

#define H 256
#define H3 768
#define NBATCH 32
#define TIN 50
#define TTGT 40
#define TTAG 20
#define VSZ 50003
#define VP 50048          // padded to 64
#define NT 782            // VP / 64
#define MT 1280           // TTGT * NBATCH
#define NBLK 16           // blocks per GRU group

typedef float f32x4 __attribute__((ext_vector_type(4)));
typedef short short8 __attribute__((ext_vector_type(8)));

__device__ __forceinline__ float dot4(float4 a, float4 b) {
    return a.x * b.x + a.y * b.y + a.z * b.z + a.w * b.w;
}

// ---------------- device-scope grid barrier (per-group) --------------------
__device__ __forceinline__ void gbar(int* bar, int nb) {
    __syncthreads();
    if (threadIdx.x == 0) {
        __threadfence();
        int gen = __hip_atomic_load(&bar[1], __ATOMIC_RELAXED, __HIP_MEMORY_SCOPE_AGENT);
        int prev = __hip_atomic_fetch_add(&bar[0], 1, __ATOMIC_ACQ_REL, __HIP_MEMORY_SCOPE_AGENT);
        if (prev == nb - 1) {
            __hip_atomic_store(&bar[0], 0, __ATOMIC_RELAXED, __HIP_MEMORY_SCOPE_AGENT);
            __hip_atomic_fetch_add(&bar[1], 1, __ATOMIC_RELEASE, __HIP_MEMORY_SCOPE_AGENT);
        } else {
            while (__hip_atomic_load(&bar[1], __ATOMIC_ACQUIRE, __HIP_MEMORY_SCOPE_AGENT) == gen)
                __builtin_amdgcn_s_sleep(2);
        }
    }
    __syncthreads();
}

// ---------------- weight transpose: src[N][K] -> dst[(k/4)][N][4] ----------
// 3 Wih mats (768x256) + proj (256x512)
__global__ void k_transpose(const float* s0, const float* s1, const float* s2,
                            const float* s3, float* d0, float* d1, float* d2,
                            float* d3) {
    int which = blockIdx.y;
    const float* s;
    float* d;
    int N, K;
    switch (which) {
        case 0: s = s0; d = d0; N = H3; K = H; break;
        case 1: s = s1; d = d1; N = H3; K = H; break;
        case 2: s = s2; d = d2; N = H3; K = H; break;
        default: s = s3; d = d3; N = H; K = 2 * H; break;
    }
    int n = blockIdx.x;
    if (n >= N) return;
    for (int k = threadIdx.x; k < K; k += 256)
        d[(size_t)(k >> 2) * (N * 4) + n * 4 + (k & 3)] = s[(size_t)n * K + k];
}

// ---------------- Whh f32 -> bf16 row-major (3 mats) -----------------------
__global__ void k_cvt_whh(const float* s0, const float* s1, const float* s2,
                          __hip_bfloat16* d0, __hip_bfloat16* d1,
                          __hip_bfloat16* d2) {
    int which = blockIdx.y;
    const float* s = which == 0 ? s0 : (which == 1 ? s1 : s2);
    __hip_bfloat16* d = which == 0 ? d0 : (which == 1 ? d1 : d2);
    size_t i = (size_t)blockIdx.x * H + threadIdx.x;
    d[i] = __float2bfloat16(s[i]);
}

// ---------------- out_W f32 -> bf16 padded [VP][H]; zero barriers ----------
__global__ void k_cvt_outw(const float* W, __hip_bfloat16* out, int* bars) {
    if (blockIdx.x == 0 && threadIdx.x < 64) bars[threadIdx.x] = 0;
    int i4 = (blockIdx.x * 256 + threadIdx.x) * 4;
    if (i4 >= VP * H) return;
    int row = i4 >> 8;
    float4 v;
    if (row < VSZ) v = *(const float4*)(W + i4);
    else v = make_float4(0.f, 0.f, 0.f, 0.f);
    out[i4 + 0] = __float2bfloat16(v.x);
    out[i4 + 1] = __float2bfloat16(v.y);
    out[i4 + 2] = __float2bfloat16(v.z);
    out[i4 + 3] = __float2bfloat16(v.w);
}

// ---------------- gi = emb[toks] @ Wih^T + bih -----------------------------
// grid (T, 3 gates), block 256.  mode: 0 = plain, 2 = decoder (BOS shift + relu)
__global__ __launch_bounds__(256) void k_gi(const int* toks, int mode,
                                            const float* emb, const float* W4,
                                            const float* bih, float* gi) {
    __shared__ float x[NBATCH][H];
    int t = blockIdx.x, g = blockIdx.y, tid = threadIdx.x;
    for (int b = 0; b < NBATCH; ++b) {
        int tok;
        if (mode == 2) tok = (t == 0) ? 1 : toks[(t - 1) * NBATCH + b];
        else tok = toks[t * NBATCH + b];
        float v = emb[(size_t)tok * H + tid];
        if (mode == 2) v = fmaxf(v, 0.0f);
        x[b][tid] = v;
    }
    __syncthreads();
    int nb_ = tid & 63, mg = tid >> 6;
    float acc[4][8];
#pragma unroll
    for (int j = 0; j < 4; ++j)
#pragma unroll
        for (int mi = 0; mi < 8; ++mi) acc[j][mi] = 0.f;

    for (int k4 = 0; k4 < 64; ++k4) {
        const float4* wrow = (const float4*)(W4 + (size_t)k4 * 3072);
        float4 w0 = wrow[g * 256 + nb_];
        float4 w1 = wrow[g * 256 + nb_ + 64];
        float4 w2 = wrow[g * 256 + nb_ + 128];
        float4 w3 = wrow[g * 256 + nb_ + 192];
#pragma unroll
        for (int mi = 0; mi < 8; ++mi) {
            float4 xv = *(const float4*)&x[mg * 8 + mi][k4 * 4];
            acc[0][mi] += dot4(xv, w0);
            acc[1][mi] += dot4(xv, w1);
            acc[2][mi] += dot4(xv, w2);
            acc[3][mi] += dot4(xv, w3);
        }
    }
#pragma unroll
    for (int j = 0; j < 4; ++j) {
        int n = g * 256 + nb_ + j * 64;
        float bv = bih[n];
#pragma unroll
        for (int mi = 0; mi < 8; ++mi) {
            int m = t * NBATCH + mg * 8 + mi;
            gi[(size_t)m * H3 + n] = acc[j][mi] + bv;
        }
    }
}

// ---------------- persistent GRU scan with grid barrier --------------------
// Two groups per launch: blocks [0,nset1) = set1, rest = set2.
// Each block owns 16 h-cols (48 gate rows).  512 threads.
// hb: bf16 [(T+1)][32][256] sequence buffer; step t reads slice t, writes t+1.
__global__ __launch_bounds__(512) void k_scan(
    int nset1,
    const float* gi1, const __hip_bfloat16* W1, const float* bhh1,
    const float* h01, float* hT1, __hip_bfloat16* hb1, int T1, int* bar1,
    const float* gi2, const __hip_bfloat16* W2, const float* bhh2,
    const float* h02, float* hT2, __hip_bfloat16* hb2, int T2, int* bar2) {
    __shared__ uint4 WL[48 * 32];     // 24KB swizzled bf16 weight slice
    __shared__ float C[32][48];       // 6KB f32 gate pre-activations
    int blk = blockIdx.x, tid = threadIdx.x;
    const float *gi, *bhh, *h0;
    const __hip_bfloat16* Wg;
    float* hT;
    __hip_bfloat16* hb;
    int T, j;
    int* bar;
    if (blk < nset1) {
        gi = gi1; Wg = W1; bhh = bhh1; h0 = h01; hT = hT1; hb = hb1; T = T1;
        bar = bar1; j = blk;
    } else {
        gi = gi2; Wg = W2; bhh = bhh2; h0 = h02; hT = hT2; hb = hb2; T = T2;
        bar = bar2; j = blk - nset1;
    }
    int c0 = j * 16;
    // load 48-row weight slice into LDS (XOR-swizzled rows of 32 uint4)
#pragma unroll
    for (int i = 0; i < 3; ++i) {
        int idx = tid + i * 512;
        int r = idx >> 5, g = idx & 31;
        int grow = (r >> 4) * 256 + c0 + (r & 15);
        WL[(r << 5) | (g ^ (r & 7))] = ((const uint4*)Wg)[grow * 32 + g];
    }
    int b = tid >> 4, cl = tid & 15, c = c0 + cl;
    float br = bhh[c], bz = bhh[H + c], bn = bhh[2 * H + c];
    float h = h0 ? h0[b * H + c] : 0.0f;
    hb[b * H + c] = __float2bfloat16(h);
    // prefetch gi for t=0
    size_t gm = (size_t)b * H3;
    float gr = gi[gm + c], gz = gi[gm + H + c], gn = gi[gm + 2 * H + c];
    gbar(bar, NBLK);

    int wave = tid >> 6, lane = tid & 63, lr = lane & 15, lg = lane >> 4;
    int mt = wave >= 3 ? 1 : 0, nt = wave - mt * 3;  // valid for wave<6
    const short8* BL = (const short8*)WL;
    for (int t = 0; t < T; ++t) {
        if (wave < 6) {
            const short8* Arow = (const short8*)(hb + (size_t)t * 8192);
            f32x4 acc = (f32x4){0.f, 0.f, 0.f, 0.f};
            int ra = mt * 16 + lr;   // batch row
            int rb = nt * 16 + lr;   // local gate row
#pragma unroll
            for (int ks = 0; ks < 8; ++ks) {
                int ga = ks * 4 + lg;
                short8 av = Arow[ra * 32 + ga];
                short8 bv = BL[(rb << 5) | (ga ^ (rb & 7))];
                acc = __builtin_amdgcn_mfma_f32_16x16x32_bf16(av, bv, acc, 0, 0, 0);
            }
#pragma unroll
            for (int reg = 0; reg < 4; ++reg)
                C[mt * 16 + lg * 4 + reg][nt * 16 + lr] = acc[reg];
        }
        __syncthreads();
        float ar = C[b][cl], az = C[b][16 + cl], an = C[b][32 + cl];
        float r = 1.0f / (1.0f + expf(-(gr + br + ar)));
        float z = 1.0f / (1.0f + expf(-(gz + bz + az)));
        float nn = tanhf(gn + bn + r * an);
        h = (1.0f - z) * nn + z * h;
        hb[(size_t)(t + 1) * 8192 + b * H + c] = __float2bfloat16(h);
        if (t + 1 < T) {
            size_t m = (size_t)((t + 1) * NBATCH + b) * H3;
            gr = gi[m + c]; gz = gi[m + H + c]; gn = gi[m + 2 * H + c];
        }
        gbar(bar, NBLK);
    }
    if (hT) hT[b * H + c] = h;
}

// ---------------- merged = concat(tag_h, enc_h) @ proj_W^T + proj_b --------
__global__ void k_proj(const float* tag_h, const float* enc_h,
                       const float* W4p, const float* pb, float* merged) {
    __shared__ float c[2 * H];
    int b = blockIdx.x, tid = threadIdx.x;
    c[tid] = tag_h[b * H + tid];
    c[H + tid] = enc_h[b * H + tid];
    __syncthreads();
    float acc = 0.f;
#pragma unroll 4
    for (int k4 = 0; k4 < 128; ++k4) {
        float4 cv = *(const float4*)&c[k4 * 4];
        float4 wv = ((const float4*)(W4p + (size_t)k4 * 1024))[tid];
        acc += dot4(cv, wv);
    }
    merged[b * H + tid] = acc + pb[tid];
}

// ---------------- logits GEMM: C[1280][50003] = A @ Bw^T + bias ------------
// A: bf16 [1280][256], Bw: bf16 [VP][256]. 64x64 tile, K=256, bf16 MFMA.
__global__ __launch_bounds__(256) void k_logits(const __hip_bfloat16* A,
                                                const __hip_bfloat16* Bw,
                                                const float* bias, float* dout,
                                                float* pmax, float* psum) {
    __shared__ uint4 smem[4096];  // 32KB A-tile + 32KB B-tile
    int bid = blockIdx.x;
    // XCD-aware bijective swizzle: 15640 = 8 * 1955
    int wg = (bid & 7) * 1955 + (bid >> 3);
    int nblk = wg / 20, mblk = wg % 20;  // N-major: 20 M-tiles share a B-tile
    int m0 = mblk * 64, n0 = nblk * 64;
    int tid = threadIdx.x;
    const uint4* Ag = (const uint4*)(A + (size_t)m0 * H);
    const uint4* Bg = (const uint4*)(Bw + (size_t)n0 * H);
#pragma unroll
    for (int i = 0; i < 8; ++i) {
        int c = tid + i * 256;
        int r = c >> 5, g = c & 31;
        smem[(r << 5) | (g ^ (r & 7))] = Ag[c];
    }
#pragma unroll
    for (int i = 0; i < 8; ++i) {
        int c = tid + i * 256;
        int r = c >> 5, g = c & 31;
        smem[2048 + ((r << 5) | (g ^ (r & 7)))] = Bg[c];
    }
    __syncthreads();
    int wave = tid >> 6, lane = tid & 63, lr = lane & 15, lg = lane >> 4;
    f32x4 acc[4];
#pragma unroll
    for (int ns = 0; ns < 4; ++ns) acc[ns] = (f32x4){0.f, 0.f, 0.f, 0.f};
    const short8* L = (const short8*)smem;
    int ra = wave * 16 + lr;
#pragma unroll
    for (int ks = 0; ks < 8; ++ks) {
        int ga = ks * 4 + lg;
        short8 av = L[(ra << 5) | (ga ^ (ra & 7))];
#pragma unroll
        for (int ns = 0; ns < 4; ++ns) {
            int rb = ns * 16 + lr;
            short8 bv = L[2048 + ((rb << 5) | (ga ^ (rb & 7)))];
            acc[ns] = __builtin_amdgcn_mfma_f32_16x16x32_bf16(av, bv, acc[ns], 0, 0, 0);
        }
    }
    // epilogue: bias + store f32 logits + per-row LSE partials for this tile
    float biasv[4];
    bool valid[4];
    int nn[4];
#pragma unroll
    for (int ns = 0; ns < 4; ++ns) {
        int n = n0 + ns * 16 + lr;
        nn[ns] = n;
        valid[ns] = (n < VSZ);
        biasv[ns] = valid[ns] ? bias[n] : 0.f;
    }
#pragma unroll
    for (int reg = 0; reg < 4; ++reg) {
        int m = m0 + wave * 16 + lg * 4 + reg;
        float v[4];
        float rm = -INFINITY;
#pragma unroll
        for (int ns = 0; ns < 4; ++ns) {
            v[ns] = acc[ns][reg] + biasv[ns];
            if (valid[ns]) {
                dout[2 + (size_t)m * VSZ + nn[ns]] = v[ns];
                rm = fmaxf(rm, v[ns]);
            }
        }
        for (int off = 1; off < 16; off <<= 1) rm = fmaxf(rm, __shfl_xor(rm, off));
        float se = 0.f;
#pragma unroll
        for (int ns = 0; ns < 4; ++ns)
            if (valid[ns]) se += expf(v[ns] - rm);
        for (int off = 1; off < 16; off <<= 1) se += __shfl_xor(se, off);
        if (lr == 0) {
            pmax[(size_t)m * NT + nblk] = rm;
            psum[(size_t)m * NT + nblk] = se;
        }
    }
}

// ---------------- per-row logsumexp from tile partials ---------------------
__global__ void k_lse(const float* pmax, const float* psum, float* lse) {
    int m = blockIdx.x, tid = threadIdx.x;
    __shared__ float sm[4];
    float lm = -INFINITY;
    for (int i = tid; i < NT; i += 256) lm = fmaxf(lm, pmax[(size_t)m * NT + i]);
    for (int off = 1; off < 64; off <<= 1) lm = fmaxf(lm, __shfl_xor(lm, off));
    if ((tid & 63) == 0) sm[tid >> 6] = lm;
    __syncthreads();
    float M = fmaxf(fmaxf(sm[0], sm[1]), fmaxf(sm[2], sm[3]));
    __syncthreads();
    float s = 0.f;
    for (int i = tid; i < NT; i += 256)
        s += psum[(size_t)m * NT + i] * expf(pmax[(size_t)m * NT + i] - M);
    for (int off = 1; off < 64; off <<= 1) s += __shfl_xor(s, off);
    if ((tid & 63) == 0) sm[tid >> 6] = s;
    __syncthreads();
    if (tid == 0) lse[m] = M + logf(sm[0] + sm[1] + sm[2] + sm[3]);
}

// ---------------- final NLL loss -------------------------------------------
__global__ void k_loss(const float* lse, const int* tgt, float* dout) {
    int tid = threadIdx.x;
    __shared__ float sm[4];
    float s = 0.f;
    for (int m = tid; m < MT; m += 256) {
        int tg = tgt[m];
        s += lse[m] - dout[2 + (size_t)m * VSZ + tg];
    }
    for (int off = 1; off < 64; off <<= 1) s += __shfl_xor(s, off);
    if ((tid & 63) == 0) sm[tid >> 6] = s;
    __syncthreads();
    if (tid == 0) {
        float total = sm[0] + sm[1] + sm[2] + sm[3];
        dout[0] = total / 32.0f;    // sum over t of mean over batch
        dout[1] = total / 1280.0f;  // / T_tgt
    }
}

// ---------------------------------------------------------------------------
extern "C" void kernel_launch(void* const* d_in, const int* in_sizes, int n_in,
                              void* d_out, int out_size, void* d_ws,
                              size_t ws_size, hipStream_t stream) {
    const int* input_tensor = (const int*)d_in[0];
    const int* target_tensor = (const int*)d_in[1];
    const int* tag_tensor = (const int*)d_in[2];
    const float* enc_emb = (const float*)d_in[3];
    const float* enc_Wih = (const float*)d_in[4];
    const float* enc_Whh = (const float*)d_in[5];
    const float* enc_bih = (const float*)d_in[6];
    const float* enc_bhh = (const float*)d_in[7];
    const float* tag_emb = (const float*)d_in[8];
    const float* tag_Wih = (const float*)d_in[9];
    const float* tag_Whh = (const float*)d_in[10];
    const float* tag_bih = (const float*)d_in[11];
    const float* tag_bhh = (const float*)d_in[12];
    const float* proj_W = (const float*)d_in[13];
    const float* proj_b = (const float*)d_in[14];
    const float* dec_Wih = (const float*)d_in[15];
    const float* dec_Whh = (const float*)d_in[16];
    const float* dec_bih = (const float*)d_in[17];
    const float* dec_bhh = (const float*)d_in[18];
    const float* out_W = (const float*)d_in[19];
    const float* out_b = (const float*)d_in[20];

    char* wsb = (char*)d_ws;
    size_t o = 0;
    auto alloc = [&](size_t bytes) {
        size_t r = o;
        o += (bytes + 511) & ~(size_t)511;
        return r;
    };
    float* W4_enc_ih = (float*)(wsb + alloc(H3 * H * 4));
    float* W4_tag_ih = (float*)(wsb + alloc(H3 * H * 4));
    float* W4_dec_ih = (float*)(wsb + alloc(H3 * H * 4));
    float* W4_proj   = (float*)(wsb + alloc(H * 2 * H * 4));
    float* gi_enc = (float*)(wsb + alloc((size_t)TIN * NBATCH * H3 * 4));
    float* gi_tag = (float*)(wsb + alloc((size_t)TTAG * NBATCH * H3 * 4));
    float* gi_dec = (float*)(wsb + alloc((size_t)TTGT * NBATCH * H3 * 4));
    float* enc_h  = (float*)(wsb + alloc(NBATCH * H * 4));
    float* tag_h  = (float*)(wsb + alloc(NBATCH * H * 4));
    float* merged = (float*)(wsb + alloc(NBATCH * H * 4));
    float* lse    = (float*)(wsb + alloc(MT * 4));
    int*   bars   = (int*)(wsb + alloc(64 * 4));
    __hip_bfloat16* Whh_enc = (__hip_bfloat16*)(wsb + alloc(H3 * H * 2));
    __hip_bfloat16* Whh_tag = (__hip_bfloat16*)(wsb + alloc(H3 * H * 2));
    __hip_bfloat16* Whh_dec = (__hip_bfloat16*)(wsb + alloc(H3 * H * 2));
    __hip_bfloat16* outWb   = (__hip_bfloat16*)(wsb + alloc((size_t)VP * H * 2));
    __hip_bfloat16* hb_enc  = (__hip_bfloat16*)(wsb + alloc((size_t)(TIN + 1) * NBATCH * H * 2));
    __hip_bfloat16* hb_tag  = (__hip_bfloat16*)(wsb + alloc((size_t)(TTAG + 1) * NBATCH * H * 2));
    __hip_bfloat16* hb_dec  = (__hip_bfloat16*)(wsb + alloc((size_t)(TTGT + 1) * NBATCH * H * 2));
    float* pmax = (float*)(wsb + alloc((size_t)MT * NT * 4));
    float* psum = (float*)(wsb + alloc((size_t)MT * NT * 4));

    __hip_bfloat16* decA = hb_dec + NBATCH * H;  // slices 1..T = dec outputs
    float* dout = (float*)d_out;

    // 1) prep: Wih/proj transposes, Whh->bf16, out_W->bf16, zero barriers
    k_transpose<<<dim3(H3, 4), 256, 0, stream>>>(
        enc_Wih, tag_Wih, dec_Wih, proj_W, W4_enc_ih, W4_tag_ih, W4_dec_ih,
        W4_proj);
    k_cvt_whh<<<dim3(H3, 3), 256, 0, stream>>>(enc_Whh, tag_Whh, dec_Whh,
                                               Whh_enc, Whh_tag, Whh_dec);
    k_cvt_outw<<<(VP * H / 4 + 255) / 256, 256, 0, stream>>>(out_W, outWb, bars);

    // 2) gi precompute for all three GRUs
    k_gi<<<dim3(TIN, 3), 256, 0, stream>>>(input_tensor, 0, enc_emb, W4_enc_ih,
                                           enc_bih, gi_enc);
    k_gi<<<dim3(TTAG, 3), 256, 0, stream>>>(tag_tensor, 0, tag_emb, W4_tag_ih,
                                            tag_bih, gi_tag);
    k_gi<<<dim3(TTGT, 3), 256, 0, stream>>>(target_tensor, 2, enc_emb,
                                            W4_dec_ih, dec_bih, gi_dec);

    // 3) encoder + tag GRU scans (concurrent groups, 32 blocks)
    k_scan<<<2 * NBLK, 512, 0, stream>>>(
        NBLK, gi_enc, Whh_enc, enc_bhh, nullptr, enc_h, hb_enc, TIN, bars + 0,
        gi_tag, Whh_tag, tag_bhh, nullptr, tag_h, hb_tag, TTAG, bars + 16);

    // 4) proj -> merged
    k_proj<<<NBATCH, 256, 0, stream>>>(tag_h, enc_h, W4_proj, proj_b, merged);

    // 5) decoder GRU scan (writes bf16 A matrix as hb slices 1..T)
    k_scan<<<NBLK, 512, 0, stream>>>(
        NBLK, gi_dec, Whh_dec, dec_bhh, merged, nullptr, hb_dec, TTGT,
        bars + 32, nullptr, nullptr, nullptr, nullptr, nullptr, nullptr, 0,
        nullptr);

    // 6) logits GEMM + LSE partials   (grid = 782 * 20 = 15640)
    k_logits<<<NT * 20, 256, 0, stream>>>(decA, outWb, out_b, dout, pmax, psum);

    // 7) per-row logsumexp
    k_lse<<<MT, 256, 0, stream>>>(pmax, psum, lse);

    // 8) loss scalars
    k_loss<<<1, 256, 0, stream>>>(lse, target_tensor, dout);
}

// Round 3
// 649.632 us; speedup vs baseline: 1.4309x; 1.3057x over previous
//
#include <hip/hip_runtime.h>
#include <hip/hip_bf16.h>
#include <math.h>

// ---------------------------------------------------------------------------
// Seq2Seq: enc GRU (T=50) + tag GRU (T=20) -> proj -> dec GRU (T=40)
//          -> logits GEMM (1280x50003, K=256, bf16 MFMA) -> LSE -> NLL loss
//
// Round 3: GRU scan = batch-split, ZERO inter-block sync.
//   - 2 blocks per GRU, each owns 16 batch rows -> fully independent
//     recurrence, only __syncthreads() inside a block.
//   - Whh (bf16) lives entirely in REGISTERS: 8 waves x 96 gate-rows/wave
//     = 192 VGPRs of pre-permuted MFMA B-fragments (k_prep_w does the
//     permutation once).
//   - h master f32 in LDS; bf16 swizzled copy in LDS feeds MFMA A operand.
//   - bhh(r,z) folded into gi; bhh(n) folded into MFMA acc init (it is
//     inside the r*(.) term so it belongs to the recurrent preact).
// ---------------------------------------------------------------------------

#define H 256
#define H3 768
#define NBATCH 32
#define TIN 50
#define TTGT 40
#define TTAG 20
#define VSZ 50003
#define VP 50048          // padded to 64
#define NT 782            // VP / 64
#define MT 1280           // TTGT * NBATCH

typedef float f32x4 __attribute__((ext_vector_type(4)));
typedef short short8 __attribute__((ext_vector_type(8)));

__device__ __forceinline__ float dot4(float4 a, float4 b) {
    return a.x * b.x + a.y * b.y + a.z * b.z + a.w * b.w;
}

// ---------------- weight transpose: src[N][K] -> dst[(k/4)][N][4] ----------
// 3 Wih mats (768x256) + proj (256x512)
__global__ void k_transpose(const float* s0, const float* s1, const float* s2,
                            const float* s3, float* d0, float* d1, float* d2,
                            float* d3) {
    int which = blockIdx.y;
    const float* s;
    float* d;
    int N, K;
    switch (which) {
        case 0: s = s0; d = d0; N = H3; K = H; break;
        case 1: s = s1; d = d1; N = H3; K = H; break;
        case 2: s = s2; d = d2; N = H3; K = H; break;
        default: s = s3; d = d3; N = H; K = 2 * H; break;
    }
    int n = blockIdx.x;
    if (n >= N) return;
    for (int k = threadIdx.x; k < K; k += 256)
        d[(size_t)(k >> 2) * (N * 4) + n * 4 + (k & 3)] = s[(size_t)n * K + k];
}

// ---------------- Whh -> bf16 MFMA-B-fragment order ------------------------
// out[((w*48 + ks*6 + nt)*64 + lane)*8 + j] = bf16(Whh[row][k])
//   row = (nt>>1)*256 + 32*w + (nt&1)*16 + (lane&15)
//   k   = ks*32 + (lane>>4)*8 + j
__global__ void k_prep_w(const float* s0, const float* s1, const float* s2,
                         __hip_bfloat16* d0, __hip_bfloat16* d1,
                         __hip_bfloat16* d2) {
    int which = blockIdx.y;
    const float* s = which == 0 ? s0 : (which == 1 ? s1 : s2);
    __hip_bfloat16* d = which == 0 ? d0 : (which == 1 ? d1 : d2);
    int idx = blockIdx.x * 256 + threadIdx.x;      // 0..24575
    int lane = idx & 63;
    int f = (idx >> 6) % 48;
    int w = idx / (48 * 64);
    int ks = f / 6, nt = f % 6;
    int row = ((nt >> 1) << 8) + (w << 5) + ((nt & 1) << 4) + (lane & 15);
    int k = (ks << 5) + ((lane >> 4) << 3);
#pragma unroll
    for (int j = 0; j < 8; ++j)
        d[(size_t)idx * 8 + j] = __float2bfloat16(s[(size_t)row * H + k + j]);
}

// ---------------- out_W f32 -> bf16 padded [VP][H] -------------------------
__global__ void k_cvt_outw(const float* W, __hip_bfloat16* out) {
    int i4 = (blockIdx.x * 256 + threadIdx.x) * 4;
    if (i4 >= VP * H) return;
    int row = i4 >> 8;
    float4 v;
    if (row < VSZ) v = *(const float4*)(W + i4);
    else v = make_float4(0.f, 0.f, 0.f, 0.f);
    out[i4 + 0] = __float2bfloat16(v.x);
    out[i4 + 1] = __float2bfloat16(v.y);
    out[i4 + 2] = __float2bfloat16(v.z);
    out[i4 + 3] = __float2bfloat16(v.w);
}

// ---------------- gi = emb[toks] @ Wih^T + bih (+ bhh for r,z) -------------
// grid (T, 3 gates), block 256.  mode: 0 = plain, 2 = decoder (BOS shift + relu)
__global__ __launch_bounds__(256) void k_gi(const int* toks, int mode,
                                            const float* emb, const float* W4,
                                            const float* bih, const float* bhh,
                                            float* gi) {
    __shared__ float x[NBATCH][H];
    int t = blockIdx.x, g = blockIdx.y, tid = threadIdx.x;
    for (int b = 0; b < NBATCH; ++b) {
        int tok;
        if (mode == 2) tok = (t == 0) ? 1 : toks[(t - 1) * NBATCH + b];
        else tok = toks[t * NBATCH + b];
        float v = emb[(size_t)tok * H + tid];
        if (mode == 2) v = fmaxf(v, 0.0f);
        x[b][tid] = v;
    }
    __syncthreads();
    int nb_ = tid & 63, mg = tid >> 6;
    float acc[4][8];
#pragma unroll
    for (int j = 0; j < 4; ++j)
#pragma unroll
        for (int mi = 0; mi < 8; ++mi) acc[j][mi] = 0.f;

    for (int k4 = 0; k4 < 64; ++k4) {
        const float4* wrow = (const float4*)(W4 + (size_t)k4 * 3072);
        float4 w0 = wrow[g * 256 + nb_];
        float4 w1 = wrow[g * 256 + nb_ + 64];
        float4 w2 = wrow[g * 256 + nb_ + 128];
        float4 w3 = wrow[g * 256 + nb_ + 192];
#pragma unroll
        for (int mi = 0; mi < 8; ++mi) {
            float4 xv = *(const float4*)&x[mg * 8 + mi][k4 * 4];
            acc[0][mi] += dot4(xv, w0);
            acc[1][mi] += dot4(xv, w1);
            acc[2][mi] += dot4(xv, w2);
            acc[3][mi] += dot4(xv, w3);
        }
    }
#pragma unroll
    for (int j = 0; j < 4; ++j) {
        int n = g * 256 + nb_ + j * 64;
        float bv = bih[n] + (g < 2 ? bhh[n] : 0.0f);  // fold bhh for r,z only
#pragma unroll
        for (int mi = 0; mi < 8; ++mi) {
            int m = t * NBATCH + mg * 8 + mi;
            gi[(size_t)m * H3 + n] = acc[j][mi] + bv;
        }
    }
}

// ---------------- batch-split GRU scan (no inter-block sync) ---------------
// 512 threads = 8 waves.  Block handles 16 batch rows (mb = local*16).
// Wg: pre-permuted bf16 fragments.  gi has bhh(r,z) folded in.
__global__ __launch_bounds__(512, 1) void k_scan(
    int nset1,
    const float* gi1, const __hip_bfloat16* W1, const float* bhh1,
    const float* h01, float* hT1, __hip_bfloat16* out1, int T1,
    const float* gi2, const __hip_bfloat16* W2, const float* bhh2,
    const float* h02, float* hT2, __hip_bfloat16* out2, int T2) {
    __shared__ uint4 HBF[16 * 32];     // 8KB bf16 h, XOR-swizzled
    __shared__ float HF[16][264];      // 16.9KB f32 h master
    __shared__ float Cc[16][780];      // 49.9KB f32 gate preacts (pad 780)

    int blk = blockIdx.x, tid = threadIdx.x;
    const float *gi, *bhh, *h0;
    const __hip_bfloat16* Wg;
    float* hTp;
    __hip_bfloat16* outp;
    int T, loc;
    if (blk < nset1) {
        gi = gi1; Wg = W1; bhh = bhh1; h0 = h01; hTp = hT1; outp = out1;
        T = T1; loc = blk;
    } else {
        gi = gi2; Wg = W2; bhh = bhh2; h0 = h02; hTp = hT2; outp = out2;
        T = T2; loc = blk - nset1;
    }
    int mb = loc * 16;
    int w = tid >> 6, lane = tid & 63, lr = lane & 15, lg = lane >> 4;
    int lb = tid >> 5, c0 = (tid & 31) * 8, b = mb + lb;

    // load this wave's 48 weight fragments into registers (192 VGPRs)
    short8 wreg[48];
    const uint4* Wg4 = (const uint4*)Wg;
#pragma unroll
    for (int f = 0; f < 48; ++f) {
        uint4 v = Wg4[(size_t)(w * 48 + f) * 64 + lane];
        wreg[f] = *(short8*)&v;
    }
    // bhh(n) for this wave's two n-tiles (acc init)
    float bnv0 = bhh[512 + (w << 5) + lr];
    float bnv1 = bhh[512 + (w << 5) + 16 + lr];

    // init h (f32 master + bf16 swizzled copy)
    {
        float hv[8];
        if (h0) {
            *(float4*)&hv[0] = *(const float4*)(h0 + (size_t)b * H + c0);
            *(float4*)&hv[4] = *(const float4*)(h0 + (size_t)b * H + c0 + 4);
        } else {
#pragma unroll
            for (int i = 0; i < 8; ++i) hv[i] = 0.f;
        }
        *(float4*)&HF[lb][c0] = *(float4*)&hv[0];
        *(float4*)&HF[lb][c0 + 4] = *(float4*)&hv[4];
        short8 hb;
#pragma unroll
        for (int i = 0; i < 8; ++i) {
            __hip_bfloat16 q = __float2bfloat16(hv[i]);
            hb[i] = *(short*)&q;
        }
        ((short8*)HBF)[lb * 32 + ((tid & 31) ^ (lb & 7))] = hb;
    }
    __syncthreads();

    const short8* HS = (const short8*)HBF;
    for (int t = 0; t < T; ++t) {
        // ---- MFMA phase: C[16 x 768] = h @ Whh^T (+bhh_n on n-tiles) ----
        f32x4 acc[6];
        acc[0] = (f32x4){0.f, 0.f, 0.f, 0.f};
        acc[1] = acc[0];
        acc[2] = acc[0];
        acc[3] = acc[0];
        acc[4] = (f32x4){bnv0, bnv0, bnv0, bnv0};
        acc[5] = (f32x4){bnv1, bnv1, bnv1, bnv1};
#pragma unroll
        for (int ks = 0; ks < 8; ++ks) {
            int k8 = ks * 4 + lg;
            short8 a = HS[lr * 32 + (k8 ^ (lr & 7))];
#pragma unroll
            for (int nt = 0; nt < 6; ++nt)
                acc[nt] = __builtin_amdgcn_mfma_f32_16x16x32_bf16(
                    a, wreg[ks * 6 + nt], acc[nt], 0, 0, 0);
        }
#pragma unroll
        for (int nt = 0; nt < 6; ++nt) {
            int col = ((nt >> 1) << 8) + (w << 5) + ((nt & 1) << 4) + lr;
#pragma unroll
            for (int reg = 0; reg < 4; ++reg)
                Cc[lg * 4 + reg][col] = acc[nt][reg];
        }
        __syncthreads();

        // ---- pointwise: 8 h-elements per thread ----
        const float* girow = gi + (size_t)(t * NBATCH + b) * H3 + c0;
        float gr[8], gz[8], gn[8], cr[8], cz[8], cn[8], ho[8], hn[8];
        *(float4*)&gr[0] = *(const float4*)(girow);
        *(float4*)&gr[4] = *(const float4*)(girow + 4);
        *(float4*)&gz[0] = *(const float4*)(girow + 256);
        *(float4*)&gz[4] = *(const float4*)(girow + 260);
        *(float4*)&gn[0] = *(const float4*)(girow + 512);
        *(float4*)&gn[4] = *(const float4*)(girow + 516);
        *(float4*)&cr[0] = *(const float4*)&Cc[lb][c0];
        *(float4*)&cr[4] = *(const float4*)&Cc[lb][c0 + 4];
        *(float4*)&cz[0] = *(const float4*)&Cc[lb][256 + c0];
        *(float4*)&cz[4] = *(const float4*)&Cc[lb][256 + c0 + 4];
        *(float4*)&cn[0] = *(const float4*)&Cc[lb][512 + c0];
        *(float4*)&cn[4] = *(const float4*)&Cc[lb][512 + c0 + 4];
        *(float4*)&ho[0] = *(const float4*)&HF[lb][c0];
        *(float4*)&ho[4] = *(const float4*)&HF[lb][c0 + 4];
#pragma unroll
        for (int i = 0; i < 8; ++i) {
            float r = 1.0f / (1.0f + __expf(-(gr[i] + cr[i])));
            float z = 1.0f / (1.0f + __expf(-(gz[i] + cz[i])));
            float x = gn[i] + r * cn[i];
            float e2 = __expf(-2.0f * fabsf(x));
            float n = copysignf((1.0f - e2) / (1.0f + e2), x);
            hn[i] = (1.0f - z) * n + z * ho[i];
        }
        *(float4*)&HF[lb][c0] = *(float4*)&hn[0];
        *(float4*)&HF[lb][c0 + 4] = *(float4*)&hn[4];
        short8 hb;
#pragma unroll
        for (int i = 0; i < 8; ++i) {
            __hip_bfloat16 q = __float2bfloat16(hn[i]);
            hb[i] = *(short*)&q;
        }
        ((short8*)HBF)[lb * 32 + ((tid & 31) ^ (lb & 7))] = hb;
        if (outp)
            *(short8*)(outp + (size_t)(t * NBATCH + b) * H + c0) = hb;
        if (hTp && t == T - 1) {
            *(float4*)(hTp + (size_t)b * H + c0) = *(float4*)&hn[0];
            *(float4*)(hTp + (size_t)b * H + c0 + 4) = *(float4*)&hn[4];
        }
        __syncthreads();
    }
}

// ---------------- merged = concat(tag_h, enc_h) @ proj_W^T + proj_b --------
__global__ void k_proj(const float* tag_h, const float* enc_h,
                       const float* W4p, const float* pb, float* merged) {
    __shared__ float c[2 * H];
    int b = blockIdx.x, tid = threadIdx.x;
    c[tid] = tag_h[b * H + tid];
    c[H + tid] = enc_h[b * H + tid];
    __syncthreads();
    float acc = 0.f;
#pragma unroll 4
    for (int k4 = 0; k4 < 128; ++k4) {
        float4 cv = *(const float4*)&c[k4 * 4];
        float4 wv = ((const float4*)(W4p + (size_t)k4 * 1024))[tid];
        acc += dot4(cv, wv);
    }
    merged[b * H + tid] = acc + pb[tid];
}

// ---------------- logits GEMM: C[1280][50003] = A @ Bw^T + bias ------------
// A: bf16 [1280][256], Bw: bf16 [VP][256]. 64x64 tile, K=256, bf16 MFMA.
__global__ __launch_bounds__(256) void k_logits(const __hip_bfloat16* A,
                                                const __hip_bfloat16* Bw,
                                                const float* bias, float* dout,
                                                float* pmax, float* psum) {
    __shared__ uint4 smem[4096];  // 32KB A-tile + 32KB B-tile
    int bid = blockIdx.x;
    // XCD-aware bijective swizzle: 15640 = 8 * 1955
    int wg = (bid & 7) * 1955 + (bid >> 3);
    int nblk = wg / 20, mblk = wg % 20;  // N-major: 20 M-tiles share a B-tile
    int m0 = mblk * 64, n0 = nblk * 64;
    int tid = threadIdx.x;
    const uint4* Ag = (const uint4*)(A + (size_t)m0 * H);
    const uint4* Bg = (const uint4*)(Bw + (size_t)n0 * H);
#pragma unroll
    for (int i = 0; i < 8; ++i) {
        int c = tid + i * 256;
        int r = c >> 5, g = c & 31;
        smem[(r << 5) | (g ^ (r & 7))] = Ag[c];
    }
#pragma unroll
    for (int i = 0; i < 8; ++i) {
        int c = tid + i * 256;
        int r = c >> 5, g = c & 31;
        smem[2048 + ((r << 5) | (g ^ (r & 7)))] = Bg[c];
    }
    __syncthreads();
    int wave = tid >> 6, lane = tid & 63, lr = lane & 15, lg = lane >> 4;
    f32x4 acc[4];
#pragma unroll
    for (int ns = 0; ns < 4; ++ns) acc[ns] = (f32x4){0.f, 0.f, 0.f, 0.f};
    const short8* L = (const short8*)smem;
    int ra = wave * 16 + lr;
#pragma unroll
    for (int ks = 0; ks < 8; ++ks) {
        int ga = ks * 4 + lg;
        short8 av = L[(ra << 5) | (ga ^ (ra & 7))];
#pragma unroll
        for (int ns = 0; ns < 4; ++ns) {
            int rb = ns * 16 + lr;
            short8 bv = L[2048 + ((rb << 5) | (ga ^ (rb & 7)))];
            acc[ns] = __builtin_amdgcn_mfma_f32_16x16x32_bf16(av, bv, acc[ns], 0, 0, 0);
        }
    }
    // epilogue: bias + store f32 logits + per-row LSE partials for this tile
    float biasv[4];
    bool valid[4];
    int nn[4];
#pragma unroll
    for (int ns = 0; ns < 4; ++ns) {
        int n = n0 + ns * 16 + lr;
        nn[ns] = n;
        valid[ns] = (n < VSZ);
        biasv[ns] = valid[ns] ? bias[n] : 0.f;
    }
#pragma unroll
    for (int reg = 0; reg < 4; ++reg) {
        int m = m0 + wave * 16 + lg * 4 + reg;
        float v[4];
        float rm = -INFINITY;
#pragma unroll
        for (int ns = 0; ns < 4; ++ns) {
            v[ns] = acc[ns][reg] + biasv[ns];
            if (valid[ns]) {
                dout[2 + (size_t)m * VSZ + nn[ns]] = v[ns];
                rm = fmaxf(rm, v[ns]);
            }
        }
        for (int off = 1; off < 16; off <<= 1) rm = fmaxf(rm, __shfl_xor(rm, off));
        float se = 0.f;
#pragma unroll
        for (int ns = 0; ns < 4; ++ns)
            if (valid[ns]) se += expf(v[ns] - rm);
        for (int off = 1; off < 16; off <<= 1) se += __shfl_xor(se, off);
        if (lr == 0) {
            pmax[(size_t)m * NT + nblk] = rm;
            psum[(size_t)m * NT + nblk] = se;
        }
    }
}

// ---------------- per-row logsumexp from tile partials ---------------------
__global__ void k_lse(const float* pmax, const float* psum, float* lse) {
    int m = blockIdx.x, tid = threadIdx.x;
    __shared__ float sm[4];
    float lm = -INFINITY;
    for (int i = tid; i < NT; i += 256) lm = fmaxf(lm, pmax[(size_t)m * NT + i]);
    for (int off = 1; off < 64; off <<= 1) lm = fmaxf(lm, __shfl_xor(lm, off));
    if ((tid & 63) == 0) sm[tid >> 6] = lm;
    __syncthreads();
    float M = fmaxf(fmaxf(sm[0], sm[1]), fmaxf(sm[2], sm[3]));
    __syncthreads();
    float s = 0.f;
    for (int i = tid; i < NT; i += 256)
        s += psum[(size_t)m * NT + i] * expf(pmax[(size_t)m * NT + i] - M);
    for (int off = 1; off < 64; off <<= 1) s += __shfl_xor(s, off);
    if ((tid & 63) == 0) sm[tid >> 6] = s;
    __syncthreads();
    if (tid == 0) lse[m] = M + logf(sm[0] + sm[1] + sm[2] + sm[3]);
}

// ---------------- final NLL loss -------------------------------------------
__global__ void k_loss(const float* lse, const int* tgt, float* dout) {
    int tid = threadIdx.x;
    __shared__ float sm[4];
    float s = 0.f;
    for (int m = tid; m < MT; m += 256) {
        int tg = tgt[m];
        s += lse[m] - dout[2 + (size_t)m * VSZ + tg];
    }
    for (int off = 1; off < 64; off <<= 1) s += __shfl_xor(s, off);
    if ((tid & 63) == 0) sm[tid >> 6] = s;
    __syncthreads();
    if (tid == 0) {
        float total = sm[0] + sm[1] + sm[2] + sm[3];
        dout[0] = total / 32.0f;    // sum over t of mean over batch
        dout[1] = total / 1280.0f;  // / T_tgt
    }
}

// ---------------------------------------------------------------------------
extern "C" void kernel_launch(void* const* d_in, const int* in_sizes, int n_in,
                              void* d_out, int out_size, void* d_ws,
                              size_t ws_size, hipStream_t stream) {
    const int* input_tensor = (const int*)d_in[0];
    const int* target_tensor = (const int*)d_in[1];
    const int* tag_tensor = (const int*)d_in[2];
    const float* enc_emb = (const float*)d_in[3];
    const float* enc_Wih = (const float*)d_in[4];
    const float* enc_Whh = (const float*)d_in[5];
    const float* enc_bih = (const float*)d_in[6];
    const float* enc_bhh = (const float*)d_in[7];
    const float* tag_emb = (const float*)d_in[8];
    const float* tag_Wih = (const float*)d_in[9];
    const float* tag_Whh = (const float*)d_in[10];
    const float* tag_bih = (const float*)d_in[11];
    const float* tag_bhh = (const float*)d_in[12];
    const float* proj_W = (const float*)d_in[13];
    const float* proj_b = (const float*)d_in[14];
    const float* dec_Wih = (const float*)d_in[15];
    const float* dec_Whh = (const float*)d_in[16];
    const float* dec_bih = (const float*)d_in[17];
    const float* dec_bhh = (const float*)d_in[18];
    const float* out_W = (const float*)d_in[19];
    const float* out_b = (const float*)d_in[20];

    char* wsb = (char*)d_ws;
    size_t o = 0;
    auto alloc = [&](size_t bytes) {
        size_t r = o;
        o += (bytes + 511) & ~(size_t)511;
        return r;
    };
    float* W4_enc_ih = (float*)(wsb + alloc(H3 * H * 4));
    float* W4_tag_ih = (float*)(wsb + alloc(H3 * H * 4));
    float* W4_dec_ih = (float*)(wsb + alloc(H3 * H * 4));
    float* W4_proj   = (float*)(wsb + alloc(H * 2 * H * 4));
    float* gi_enc = (float*)(wsb + alloc((size_t)TIN * NBATCH * H3 * 4));
    float* gi_tag = (float*)(wsb + alloc((size_t)TTAG * NBATCH * H3 * 4));
    float* gi_dec = (float*)(wsb + alloc((size_t)TTGT * NBATCH * H3 * 4));
    float* enc_h  = (float*)(wsb + alloc(NBATCH * H * 4));
    float* tag_h  = (float*)(wsb + alloc(NBATCH * H * 4));
    float* merged = (float*)(wsb + alloc(NBATCH * H * 4));
    float* lse    = (float*)(wsb + alloc(MT * 4));
    __hip_bfloat16* Wp_enc = (__hip_bfloat16*)(wsb + alloc(H3 * H * 2));
    __hip_bfloat16* Wp_tag = (__hip_bfloat16*)(wsb + alloc(H3 * H * 2));
    __hip_bfloat16* Wp_dec = (__hip_bfloat16*)(wsb + alloc(H3 * H * 2));
    __hip_bfloat16* outWb  = (__hip_bfloat16*)(wsb + alloc((size_t)VP * H * 2));
    __hip_bfloat16* decA   = (__hip_bfloat16*)(wsb + alloc((size_t)MT * H * 2));
    float* pmax = (float*)(wsb + alloc((size_t)MT * NT * 4));
    float* psum = (float*)(wsb + alloc((size_t)MT * NT * 4));

    float* dout = (float*)d_out;

    // 1) prep: Wih/proj transposes, Whh -> fragment bf16, out_W -> bf16
    k_transpose<<<dim3(H3, 4), 256, 0, stream>>>(
        enc_Wih, tag_Wih, dec_Wih, proj_W, W4_enc_ih, W4_tag_ih, W4_dec_ih,
        W4_proj);
    k_prep_w<<<dim3(96, 3), 256, 0, stream>>>(enc_Whh, tag_Whh, dec_Whh,
                                              Wp_enc, Wp_tag, Wp_dec);
    k_cvt_outw<<<(VP * H / 4 + 255) / 256, 256, 0, stream>>>(out_W, outWb);

    // 2) gi precompute for all three GRUs (bhh r,z folded in)
    k_gi<<<dim3(TIN, 3), 256, 0, stream>>>(input_tensor, 0, enc_emb, W4_enc_ih,
                                           enc_bih, enc_bhh, gi_enc);
    k_gi<<<dim3(TTAG, 3), 256, 0, stream>>>(tag_tensor, 0, tag_emb, W4_tag_ih,
                                            tag_bih, tag_bhh, gi_tag);
    k_gi<<<dim3(TTGT, 3), 256, 0, stream>>>(target_tensor, 2, enc_emb,
                                            W4_dec_ih, dec_bih, dec_bhh,
                                            gi_dec);

    // 3) encoder + tag GRU scans (4 independent blocks, no grid sync)
    k_scan<<<4, 512, 0, stream>>>(
        2, gi_enc, Wp_enc, enc_bhh, nullptr, enc_h, nullptr, TIN,
        gi_tag, Wp_tag, tag_bhh, nullptr, tag_h, nullptr, TTAG);

    // 4) proj -> merged
    k_proj<<<NBATCH, 256, 0, stream>>>(tag_h, enc_h, W4_proj, proj_b, merged);

    // 5) decoder GRU scan (2 blocks, writes bf16 A matrix)
    k_scan<<<2, 512, 0, stream>>>(
        2, gi_dec, Wp_dec, dec_bhh, merged, nullptr, decA, TTGT,
        nullptr, nullptr, nullptr, nullptr, nullptr, nullptr, 0);

    // 6) logits GEMM + LSE partials   (grid = 782 * 20 = 15640)
    k_logits<<<NT * 20, 256, 0, stream>>>(decA, outWb, out_b, dout, pmax, psum);

    // 7) per-row logsumexp
    k_lse<<<MT, 256, 0, stream>>>(pmax, psum, lse);

    // 8) loss scalars
    k_loss<<<1, 256, 0, stream>>>(lse, target_tensor, dout);
}

// Round 4
// 636.126 us; speedup vs baseline: 1.4612x; 1.0212x over previous
//
#include <hip/hip_runtime.h>
#include <hip/hip_bf16.h>
#include <math.h>

// ---------------------------------------------------------------------------
// Seq2Seq: enc GRU (T=50) + tag GRU (T=20) -> proj -> dec GRU (T=40)
//          -> logits GEMM (1280x50003, K=256, bf16 MFMA) -> LSE -> NLL loss
//
// Round 4:
//  * k_logits: A direct global->reg (L2-hot), B in swizzled LDS, per-wave
//    LDS-staged epilogue with row-contiguous 256B wave stores, __expf.
//    LDS 49.4KB -> 3 blocks/CU.
//  * k_scan: gi(t+1) register prefetch across raw lgkm-only barriers
//    (no vmcnt drain), MFMA in two 3-acc halves to cap VGPRs.
//  * cvt_outw fused into gi launch; prep_w fused into transpose launch.
// ---------------------------------------------------------------------------

#define H 256
#define H3 768
#define NBATCH 32
#define TIN 50
#define TTGT 40
#define TTAG 20
#define VSZ 50003
#define VP 50048          // padded to 64
#define NT 782            // VP / 64
#define MT 1280           // TTGT * NBATCH
#define NGI 330           // 110 timesteps * 3 gates
#define NCVT 12512        // VP*H/4/256

typedef float f32x4 __attribute__((ext_vector_type(4)));
typedef short short8 __attribute__((ext_vector_type(8)));

__device__ __forceinline__ float dot4(float4 a, float4 b) {
    return a.x * b.x + a.y * b.y + a.z * b.z + a.w * b.w;
}

// barrier with LDS-only drain: leaves global loads in flight (gi prefetch)
__device__ __forceinline__ void bar_lgkm() {
    asm volatile("s_waitcnt lgkmcnt(0)" ::: "memory");
    __builtin_amdgcn_s_barrier();
    asm volatile("" ::: "memory");
}

// ---------------- prep: Wih/proj transpose + Whh -> MFMA-B fragments -------
// grid (768, 7): y<4 transpose to [(k/4)][N][4]; y>=4 prep_w (x<96 active)
__global__ void k_prep(const float* eWih, const float* tWih, const float* dWih,
                       const float* projW, const float* eWhh, const float* tWhh,
                       const float* dWhh, float* d0, float* d1, float* d2,
                       float* d3, __hip_bfloat16* p0, __hip_bfloat16* p1,
                       __hip_bfloat16* p2) {
    int which = blockIdx.y;
    if (which < 4) {
        const float* s;
        float* d;
        int N, K;
        switch (which) {
            case 0: s = eWih; d = d0; N = H3; K = H; break;
            case 1: s = tWih; d = d1; N = H3; K = H; break;
            case 2: s = dWih; d = d2; N = H3; K = H; break;
            default: s = projW; d = d3; N = H; K = 2 * H; break;
        }
        int n = blockIdx.x;
        if (n >= N) return;
        for (int k = threadIdx.x; k < K; k += 256)
            d[(size_t)(k >> 2) * (N * 4) + n * 4 + (k & 3)] = s[(size_t)n * K + k];
    } else {
        if (blockIdx.x >= 96) return;
        const float* s = which == 4 ? eWhh : (which == 5 ? tWhh : dWhh);
        __hip_bfloat16* d = which == 4 ? p0 : (which == 5 ? p1 : p2);
        int idx = blockIdx.x * 256 + threadIdx.x;  // 0..24575
        int lane = idx & 63;
        int f = (idx >> 6) % 48;
        int w = idx / (48 * 64);
        int ks = f / 6, nt = f % 6;
        int row = ((nt >> 1) << 8) + (w << 5) + ((nt & 1) << 4) + (lane & 15);
        int k = (ks << 5) + ((lane >> 4) << 3);
#pragma unroll
        for (int j = 0; j < 8; ++j)
            d[(size_t)idx * 8 + j] = __float2bfloat16(s[(size_t)row * H + k + j]);
    }
}

// ---------------- gi = emb[toks] @ Wih^T + bih (+bhh r,z)  [+ outW cvt] ----
// 1D grid: [0,NGI) gi blocks (gid%3 = gate, gid/3 = timeline), rest = cvt.
__global__ __launch_bounds__(256) void k_gi_cvt(
    const int* in_toks, const int* tag_toks, const int* tgt_toks,
    const float* enc_emb, const float* tag_emb, const float* W4e,
    const float* W4t, const float* W4d, const float* bih_e, const float* bhh_e,
    const float* bih_t, const float* bhh_t, const float* bih_d,
    const float* bhh_d, float* gi_e, float* gi_t, float* gi_d,
    const float* outW, __hip_bfloat16* outWb) {
    int bx = blockIdx.x, tid = threadIdx.x;
    if (bx >= NGI) {
        int i4 = ((bx - NGI) * 256 + tid) * 4;
        if (i4 >= VP * H) return;
        int row = i4 >> 8;
        float4 v;
        if (row < VSZ) v = *(const float4*)(outW + i4);
        else v = make_float4(0.f, 0.f, 0.f, 0.f);
        outWb[i4 + 0] = __float2bfloat16(v.x);
        outWb[i4 + 1] = __float2bfloat16(v.y);
        outWb[i4 + 2] = __float2bfloat16(v.z);
        outWb[i4 + 3] = __float2bfloat16(v.w);
        return;
    }
    __shared__ float x[NBATCH][H];
    int g = bx % 3, tt = bx / 3;
    const int* toks;
    const float* emb;
    const float* W4;
    const float* bihp;
    const float* bhhp;
    float* gip;
    int t, mode;
    if (tt < TIN) {
        toks = in_toks; emb = enc_emb; W4 = W4e; bihp = bih_e; bhhp = bhh_e;
        gip = gi_e; t = tt; mode = 0;
    } else if (tt < TIN + TTAG) {
        toks = tag_toks; emb = tag_emb; W4 = W4t; bihp = bih_t; bhhp = bhh_t;
        gip = gi_t; t = tt - TIN; mode = 0;
    } else {
        toks = tgt_toks; emb = enc_emb; W4 = W4d; bihp = bih_d; bhhp = bhh_d;
        gip = gi_d; t = tt - TIN - TTAG; mode = 2;
    }
    for (int b = 0; b < NBATCH; ++b) {
        int tok;
        if (mode == 2) tok = (t == 0) ? 1 : toks[(t - 1) * NBATCH + b];
        else tok = toks[t * NBATCH + b];
        float v = emb[(size_t)tok * H + tid];
        if (mode == 2) v = fmaxf(v, 0.0f);
        x[b][tid] = v;
    }
    __syncthreads();
    int nb_ = tid & 63, mg = tid >> 6;
    float acc[4][8];
#pragma unroll
    for (int j = 0; j < 4; ++j)
#pragma unroll
        for (int mi = 0; mi < 8; ++mi) acc[j][mi] = 0.f;
    for (int k4 = 0; k4 < 64; ++k4) {
        const float4* wrow = (const float4*)(W4 + (size_t)k4 * 3072);
        float4 w0 = wrow[g * 256 + nb_];
        float4 w1 = wrow[g * 256 + nb_ + 64];
        float4 w2 = wrow[g * 256 + nb_ + 128];
        float4 w3 = wrow[g * 256 + nb_ + 192];
#pragma unroll
        for (int mi = 0; mi < 8; ++mi) {
            float4 xv = *(const float4*)&x[mg * 8 + mi][k4 * 4];
            acc[0][mi] += dot4(xv, w0);
            acc[1][mi] += dot4(xv, w1);
            acc[2][mi] += dot4(xv, w2);
            acc[3][mi] += dot4(xv, w3);
        }
    }
#pragma unroll
    for (int j = 0; j < 4; ++j) {
        int n = g * 256 + nb_ + j * 64;
        float bv = bihp[n] + (g < 2 ? bhhp[n] : 0.0f);
#pragma unroll
        for (int mi = 0; mi < 8; ++mi) {
            int m = t * NBATCH + mg * 8 + mi;
            gip[(size_t)m * H3 + n] = acc[j][mi] + bv;
        }
    }
}

// ---------------- batch-split GRU scan (no inter-block sync) ---------------
// 512 threads = 8 waves, block owns 16 batch rows. Whh in registers.
// gi(t+1) register-prefetched across lgkm-only barriers.
__global__ __launch_bounds__(512, 1) void k_scan(
    int nset1,
    const float* gi1, const __hip_bfloat16* W1, const float* bhh1,
    const float* h01, float* hT1, __hip_bfloat16* out1, int T1,
    const float* gi2, const __hip_bfloat16* W2, const float* bhh2,
    const float* h02, float* hT2, __hip_bfloat16* out2, int T2) {
    __shared__ uint4 HBF[512];     // 8KB bf16 h, XOR-swizzled
    __shared__ float Cc[16][772];  // 48.25KB f32 gate preacts (772%32==4)

    int blk = blockIdx.x, tid = threadIdx.x;
    const float *gi, *bhh, *h0;
    const __hip_bfloat16* Wg;
    float* hTp;
    __hip_bfloat16* outp;
    int T, loc;
    if (blk < nset1) {
        gi = gi1; Wg = W1; bhh = bhh1; h0 = h01; hTp = hT1; outp = out1;
        T = T1; loc = blk;
    } else {
        gi = gi2; Wg = W2; bhh = bhh2; h0 = h02; hTp = hT2; outp = out2;
        T = T2; loc = blk - nset1;
    }
    int mb = loc * 16;
    int w = tid >> 6, lane = tid & 63, lr = lane & 15, lg = lane >> 4;
    int lb = tid >> 5, c0 = (tid & 31) * 8, b = mb + lb;

    // this wave's 48 weight fragments (192 VGPRs)
    short8 wreg[48];
    const uint4* Wg4 = (const uint4*)Wg;
#pragma unroll
    for (int f = 0; f < 48; ++f) {
        uint4 v = Wg4[(size_t)(w * 48 + f) * 64 + lane];
        wreg[f] = *(short8*)&v;
    }
    float bnv0 = bhh[512 + (w << 5) + lr];
    float bnv1 = bhh[512 + (w << 5) + 16 + lr];

    float hr8[8];
    if (h0) {
        *(float4*)&hr8[0] = *(const float4*)(h0 + (size_t)b * H + c0);
        *(float4*)&hr8[4] = *(const float4*)(h0 + (size_t)b * H + c0 + 4);
    } else {
#pragma unroll
        for (int i = 0; i < 8; ++i) hr8[i] = 0.f;
    }
    {
        short8 hb;
#pragma unroll
        for (int i = 0; i < 8; ++i) {
            __hip_bfloat16 q = __float2bfloat16(hr8[i]);
            hb[i] = *(short*)&q;
        }
        ((short8*)HBF)[lb * 32 + ((tid & 31) ^ (lb & 7))] = hb;
    }
    // prefetch gi(0) into registers
    float4 g0, g1, g2, g3, g4, g5;
    {
        const float* gp = gi + (size_t)b * H3 + c0;
        g0 = *(const float4*)(gp);
        g1 = *(const float4*)(gp + 4);
        g2 = *(const float4*)(gp + 256);
        g3 = *(const float4*)(gp + 260);
        g4 = *(const float4*)(gp + 512);
        g5 = *(const float4*)(gp + 516);
    }
    __syncthreads();

    const short8* HS = (const short8*)HBF;
    for (int t = 0; t < T; ++t) {
        // ---- MFMA: C[16x768] = h @ Whh^T, two 3-acc halves (VGPR cap) ----
#pragma unroll
        for (int half = 0; half < 2; ++half) {
            f32x4 acc[3];
#pragma unroll
            for (int q = 0; q < 3; ++q) {
                int nt = half * 3 + q;
                float iv = (nt == 4) ? bnv0 : ((nt == 5) ? bnv1 : 0.0f);
                acc[q] = (f32x4){iv, iv, iv, iv};
            }
#pragma unroll
            for (int ks = 0; ks < 8; ++ks) {
                short8 a = HS[lr * 32 + ((ks * 4 + lg) ^ (lr & 7))];
#pragma unroll
                for (int q = 0; q < 3; ++q)
                    acc[q] = __builtin_amdgcn_mfma_f32_16x16x32_bf16(
                        a, wreg[ks * 6 + half * 3 + q], acc[q], 0, 0, 0);
            }
#pragma unroll
            for (int q = 0; q < 3; ++q) {
                int nt = half * 3 + q;
                int col = ((nt >> 1) << 8) + (w << 5) + ((nt & 1) << 4) + lr;
#pragma unroll
                for (int reg = 0; reg < 4; ++reg)
                    Cc[lg * 4 + reg][col] = acc[q][reg];
            }
        }
        bar_lgkm();

        // ---- pointwise ----
        float gr[8], gz[8], gn[8], cr[8], cz[8], cn[8];
        *(float4*)&gr[0] = g0; *(float4*)&gr[4] = g1;
        *(float4*)&gz[0] = g2; *(float4*)&gz[4] = g3;
        *(float4*)&gn[0] = g4; *(float4*)&gn[4] = g5;
        *(float4*)&cr[0] = *(const float4*)&Cc[lb][c0];
        *(float4*)&cr[4] = *(const float4*)&Cc[lb][c0 + 4];
        *(float4*)&cz[0] = *(const float4*)&Cc[lb][256 + c0];
        *(float4*)&cz[4] = *(const float4*)&Cc[lb][256 + c0 + 4];
        *(float4*)&cn[0] = *(const float4*)&Cc[lb][512 + c0];
        *(float4*)&cn[4] = *(const float4*)&Cc[lb][512 + c0 + 4];
#pragma unroll
        for (int i = 0; i < 8; ++i) {
            float r = 1.0f / (1.0f + __expf(-(gr[i] + cr[i])));
            float z = 1.0f / (1.0f + __expf(-(gz[i] + cz[i])));
            float xx = gn[i] + r * cn[i];
            float e2 = __expf(-2.0f * fabsf(xx));
            float n = copysignf((1.0f - e2) / (1.0f + e2), xx);
            hr8[i] = (1.0f - z) * n + z * hr8[i];
        }
        short8 hb;
#pragma unroll
        for (int i = 0; i < 8; ++i) {
            __hip_bfloat16 q = __float2bfloat16(hr8[i]);
            hb[i] = *(short*)&q;
        }
        ((short8*)HBF)[lb * 32 + ((tid & 31) ^ (lb & 7))] = hb;
        if (outp)
            *(short8*)(outp + (size_t)(t * NBATCH + b) * H + c0) = hb;
        if (hTp && t == T - 1) {
            *(float4*)(hTp + (size_t)b * H + c0) = *(float4*)&hr8[0];
            *(float4*)(hTp + (size_t)b * H + c0 + 4) = *(float4*)&hr8[4];
        }
        // prefetch gi(t+1): stays in flight across the lgkm-only barrier
        if (t + 1 < T) {
            const float* gp2 = gi + (size_t)((t + 1) * NBATCH + b) * H3 + c0;
            g0 = *(const float4*)(gp2);
            g1 = *(const float4*)(gp2 + 4);
            g2 = *(const float4*)(gp2 + 256);
            g3 = *(const float4*)(gp2 + 260);
            g4 = *(const float4*)(gp2 + 512);
            g5 = *(const float4*)(gp2 + 516);
        }
        bar_lgkm();
    }
}

// ---------------- merged = concat(tag_h, enc_h) @ proj_W^T + proj_b --------
__global__ void k_proj(const float* tag_h, const float* enc_h,
                       const float* W4p, const float* pb, float* merged) {
    __shared__ float c[2 * H];
    int b = blockIdx.x, tid = threadIdx.x;
    c[tid] = tag_h[b * H + tid];
    c[H + tid] = enc_h[b * H + tid];
    __syncthreads();
    float acc = 0.f;
#pragma unroll 4
    for (int k4 = 0; k4 < 128; ++k4) {
        float4 cv = *(const float4*)&c[k4 * 4];
        float4 wv = ((const float4*)(W4p + (size_t)k4 * 1024))[tid];
        acc += dot4(cv, wv);
    }
    merged[b * H + tid] = acc + pb[tid];
}

// ---------------- logits GEMM: C[1280][50003] = A @ Bw^T + bias ------------
// A bf16 [1280][256] direct->regs; Bw bf16 [VP][256] in swizzled LDS.
// Epilogue: per-wave LDS staging + row-contiguous coalesced dword stores.
__global__ __launch_bounds__(256) void k_logits(const __hip_bfloat16* A,
                                                const __hip_bfloat16* Bw,
                                                const float* bias, float* dout,
                                                float* pmax, float* psum) {
    __shared__ uint4 bsm[2048];       // 32KB B tile
    __shared__ float cst[4][16][68];  // 17KB per-wave C staging
    int bid = blockIdx.x;
    int wg = (bid & 7) * 1955 + (bid >> 3);  // XCD-aware bijective swizzle
    int nblk = wg / 20, mblk = wg % 20;      // N-major: 20 M-tiles per B-tile
    int m0 = mblk * 64, n0 = nblk * 64;
    int tid = threadIdx.x;
    int wave = tid >> 6, lane = tid & 63, lr = lane & 15, lg = lane >> 4;
    const uint4* Bg = (const uint4*)(Bw + (size_t)n0 * H);
#pragma unroll
    for (int i = 0; i < 8; ++i) {
        int c = tid + i * 256;
        int r = c >> 5, g = c & 31;
        bsm[(r << 5) | (g ^ (r & 7))] = Bg[c];
    }
    short8 areg[8];
    const uint4* Ar = (const uint4*)(A + (size_t)(m0 + wave * 16 + lr) * H);
#pragma unroll
    for (int ks = 0; ks < 8; ++ks) {
        uint4 v = Ar[ks * 4 + lg];
        areg[ks] = *(short8*)&v;
    }
    float biasv[4];
    bool valid[4];
#pragma unroll
    for (int ns = 0; ns < 4; ++ns) {
        int n = n0 + ns * 16 + lr;
        valid[ns] = (n < VSZ);
        biasv[ns] = valid[ns] ? bias[n] : 0.f;
    }
    __syncthreads();
    f32x4 acc[4];
#pragma unroll
    for (int ns = 0; ns < 4; ++ns) acc[ns] = (f32x4){0.f, 0.f, 0.f, 0.f};
    const short8* L = (const short8*)bsm;
#pragma unroll
    for (int ks = 0; ks < 8; ++ks) {
        int ga = ks * 4 + lg;
#pragma unroll
        for (int ns = 0; ns < 4; ++ns) {
            int rb = ns * 16 + lr;
            acc[ns] = __builtin_amdgcn_mfma_f32_16x16x32_bf16(
                areg[ks], L[(rb << 5) | (ga ^ (rb & 7))], acc[ns], 0, 0, 0);
        }
    }
    // LSE partials + stage C into this wave's LDS region
    float* cw = &cst[wave][0][0];
#pragma unroll
    for (int reg = 0; reg < 4; ++reg) {
        int m = m0 + wave * 16 + lg * 4 + reg;
        float v[4];
        float rm = -INFINITY;
#pragma unroll
        for (int ns = 0; ns < 4; ++ns) {
            v[ns] = acc[ns][reg] + biasv[ns];
            if (valid[ns]) rm = fmaxf(rm, v[ns]);
            cw[(lg * 4 + reg) * 68 + ns * 16 + lr] = v[ns];
        }
        for (int off = 1; off < 16; off <<= 1) rm = fmaxf(rm, __shfl_xor(rm, off));
        float se = 0.f;
#pragma unroll
        for (int ns = 0; ns < 4; ++ns)
            if (valid[ns]) se += __expf(v[ns] - rm);
        for (int off = 1; off < 16; off <<= 1) se += __shfl_xor(se, off);
        if (lr == 0) {
            pmax[(size_t)m * NT + nblk] = rm;
            psum[(size_t)m * NT + nblk] = se;
        }
    }
    // coalesced stores: 16 rows x 64 consecutive dwords (same-wave staging,
    // compiler inserts lgkmcnt; no barrier needed)
    float* dbase = dout + 2 + (size_t)(m0 + wave * 16) * VSZ + n0;
    bool colok = (n0 + lane < VSZ);
#pragma unroll
    for (int rl = 0; rl < 16; ++rl) {
        float val = cst[wave][rl][lane];
        if (colok) dbase[(size_t)rl * VSZ + lane] = val;
    }
}

// ---------------- per-row logsumexp from tile partials ---------------------
__global__ void k_lse(const float* pmax, const float* psum, float* lse) {
    int m = blockIdx.x, tid = threadIdx.x;
    __shared__ float sm[4];
    float lm = -INFINITY;
    for (int i = tid; i < NT; i += 256) lm = fmaxf(lm, pmax[(size_t)m * NT + i]);
    for (int off = 1; off < 64; off <<= 1) lm = fmaxf(lm, __shfl_xor(lm, off));
    if ((tid & 63) == 0) sm[tid >> 6] = lm;
    __syncthreads();
    float M = fmaxf(fmaxf(sm[0], sm[1]), fmaxf(sm[2], sm[3]));
    __syncthreads();
    float s = 0.f;
    for (int i = tid; i < NT; i += 256)
        s += psum[(size_t)m * NT + i] * __expf(pmax[(size_t)m * NT + i] - M);
    for (int off = 1; off < 64; off <<= 1) s += __shfl_xor(s, off);
    if ((tid & 63) == 0) sm[tid >> 6] = s;
    __syncthreads();
    if (tid == 0) lse[m] = M + logf(sm[0] + sm[1] + sm[2] + sm[3]);
}

// ---------------- final NLL loss -------------------------------------------
__global__ void k_loss(const float* lse, const int* tgt, float* dout) {
    int tid = threadIdx.x;
    __shared__ float sm[4];
    float s = 0.f;
    for (int m = tid; m < MT; m += 256) {
        int tg = tgt[m];
        s += lse[m] - dout[2 + (size_t)m * VSZ + tg];
    }
    for (int off = 1; off < 64; off <<= 1) s += __shfl_xor(s, off);
    if ((tid & 63) == 0) sm[tid >> 6] = s;
    __syncthreads();
    if (tid == 0) {
        float total = sm[0] + sm[1] + sm[2] + sm[3];
        dout[0] = total / 32.0f;    // sum over t of mean over batch
        dout[1] = total / 1280.0f;  // / T_tgt
    }
}

// ---------------------------------------------------------------------------
extern "C" void kernel_launch(void* const* d_in, const int* in_sizes, int n_in,
                              void* d_out, int out_size, void* d_ws,
                              size_t ws_size, hipStream_t stream) {
    const int* input_tensor = (const int*)d_in[0];
    const int* target_tensor = (const int*)d_in[1];
    const int* tag_tensor = (const int*)d_in[2];
    const float* enc_emb = (const float*)d_in[3];
    const float* enc_Wih = (const float*)d_in[4];
    const float* enc_Whh = (const float*)d_in[5];
    const float* enc_bih = (const float*)d_in[6];
    const float* enc_bhh = (const float*)d_in[7];
    const float* tag_emb = (const float*)d_in[8];
    const float* tag_Wih = (const float*)d_in[9];
    const float* tag_Whh = (const float*)d_in[10];
    const float* tag_bih = (const float*)d_in[11];
    const float* tag_bhh = (const float*)d_in[12];
    const float* proj_W = (const float*)d_in[13];
    const float* proj_b = (const float*)d_in[14];
    const float* dec_Wih = (const float*)d_in[15];
    const float* dec_Whh = (const float*)d_in[16];
    const float* dec_bih = (const float*)d_in[17];
    const float* dec_bhh = (const float*)d_in[18];
    const float* out_W = (const float*)d_in[19];
    const float* out_b = (const float*)d_in[20];

    char* wsb = (char*)d_ws;
    size_t o = 0;
    auto alloc = [&](size_t bytes) {
        size_t r = o;
        o += (bytes + 511) & ~(size_t)511;
        return r;
    };
    float* W4_enc_ih = (float*)(wsb + alloc(H3 * H * 4));
    float* W4_tag_ih = (float*)(wsb + alloc(H3 * H * 4));
    float* W4_dec_ih = (float*)(wsb + alloc(H3 * H * 4));
    float* W4_proj   = (float*)(wsb + alloc(H * 2 * H * 4));
    float* gi_enc = (float*)(wsb + alloc((size_t)TIN * NBATCH * H3 * 4));
    float* gi_tag = (float*)(wsb + alloc((size_t)TTAG * NBATCH * H3 * 4));
    float* gi_dec = (float*)(wsb + alloc((size_t)TTGT * NBATCH * H3 * 4));
    float* enc_h  = (float*)(wsb + alloc(NBATCH * H * 4));
    float* tag_h  = (float*)(wsb + alloc(NBATCH * H * 4));
    float* merged = (float*)(wsb + alloc(NBATCH * H * 4));
    float* lse    = (float*)(wsb + alloc(MT * 4));
    __hip_bfloat16* Wp_enc = (__hip_bfloat16*)(wsb + alloc(H3 * H * 2));
    __hip_bfloat16* Wp_tag = (__hip_bfloat16*)(wsb + alloc(H3 * H * 2));
    __hip_bfloat16* Wp_dec = (__hip_bfloat16*)(wsb + alloc(H3 * H * 2));
    __hip_bfloat16* outWb  = (__hip_bfloat16*)(wsb + alloc((size_t)VP * H * 2));
    __hip_bfloat16* decA   = (__hip_bfloat16*)(wsb + alloc((size_t)MT * H * 2));
    float* pmax = (float*)(wsb + alloc((size_t)MT * NT * 4));
    float* psum = (float*)(wsb + alloc((size_t)MT * NT * 4));

    float* dout = (float*)d_out;

    // 1) prep: Wih/proj transposes + Whh->fragment bf16
    k_prep<<<dim3(H3, 7), 256, 0, stream>>>(
        enc_Wih, tag_Wih, dec_Wih, proj_W, enc_Whh, tag_Whh, dec_Whh,
        W4_enc_ih, W4_tag_ih, W4_dec_ih, W4_proj, Wp_enc, Wp_tag, Wp_dec);

    // 2) gi precompute (3 GRUs) + out_W->bf16, one launch
    k_gi_cvt<<<NGI + NCVT, 256, 0, stream>>>(
        input_tensor, tag_tensor, target_tensor, enc_emb, tag_emb, W4_enc_ih,
        W4_tag_ih, W4_dec_ih, enc_bih, enc_bhh, tag_bih, tag_bhh, dec_bih,
        dec_bhh, gi_enc, gi_tag, gi_dec, out_W, outWb);

    // 3) encoder + tag GRU scans (4 independent blocks)
    k_scan<<<4, 512, 0, stream>>>(
        2, gi_enc, Wp_enc, enc_bhh, nullptr, enc_h, nullptr, TIN,
        gi_tag, Wp_tag, tag_bhh, nullptr, tag_h, nullptr, TTAG);

    // 4) proj -> merged
    k_proj<<<NBATCH, 256, 0, stream>>>(tag_h, enc_h, W4_proj, proj_b, merged);

    // 5) decoder GRU scan (writes bf16 A matrix)
    k_scan<<<2, 512, 0, stream>>>(
        2, gi_dec, Wp_dec, dec_bhh, merged, nullptr, decA, TTGT,
        nullptr, nullptr, nullptr, nullptr, nullptr, nullptr, 0);

    // 6) logits GEMM + LSE partials (grid = 782*20)
    k_logits<<<NT * 20, 256, 0, stream>>>(decA, outWb, out_b, dout, pmax, psum);

    // 7) per-row logsumexp
    k_lse<<<MT, 256, 0, stream>>>(pmax, psum, lse);

    // 8) loss scalars
    k_loss<<<1, 256, 0, stream>>>(lse, target_tensor, dout);
}

// Round 6
// 524.996 us; speedup vs baseline: 1.7705x; 1.2117x over previous
//
#include <hip/hip_runtime.h>
#include <hip/hip_bf16.h>
#include <math.h>

// ---------------------------------------------------------------------------
// Seq2Seq: enc GRU (T=50) + tag GRU (T=20) -> proj -> dec GRU (T=40)
//          -> logits GEMM (1280x50003, K=256, bf16 MFMA) -> LSE -> NLL loss
//
// Round 5 resubmit (round-5 bench died on infra: UnresponsiveContainer).
// Fix k_scan VGPR spill (round-4 VGPR_Count=128 proved wreg[48] went to
// scratch).  Pressure diet:
//   - no gi register prefetch (load in pointwise)
//   - bf16 h in LDS is the master state (no f32 register copy)
//   - MFMA in two 3-acc halves; gates computed sequentially
//   Peak ~= 192 (wreg) + 12 (acc) + ~36 temps < 256.
// ---------------------------------------------------------------------------

#define H 256
#define H3 768
#define NBATCH 32
#define TIN 50
#define TTGT 40
#define TTAG 20
#define VSZ 50003
#define VP 50048          // padded to 64
#define NT 782            // VP / 64
#define MT 1280           // TTGT * NBATCH
#define NGI 330           // 110 timesteps * 3 gates
#define NCVT 12512        // VP*H/4/256

typedef float f32x4 __attribute__((ext_vector_type(4)));
typedef short short8 __attribute__((ext_vector_type(8)));

__device__ __forceinline__ float dot4(float4 a, float4 b) {
    return a.x * b.x + a.y * b.y + a.z * b.z + a.w * b.w;
}

__device__ __forceinline__ float bf2f(short s) {
    unsigned int u = ((unsigned int)(unsigned short)s) << 16;
    return __builtin_bit_cast(float, u);
}

// barrier with LDS-only drain: leaves global ops in flight
__device__ __forceinline__ void bar_lgkm() {
    asm volatile("s_waitcnt lgkmcnt(0)" ::: "memory");
    __builtin_amdgcn_s_barrier();
    __builtin_amdgcn_sched_barrier(0);
}

// ---------------- prep: Wih/proj transpose + Whh -> MFMA-B fragments -------
// grid (768, 7): y<4 transpose to [(k/4)][N][4]; y>=4 prep_w (x<96 active)
__global__ void k_prep(const float* eWih, const float* tWih, const float* dWih,
                       const float* projW, const float* eWhh, const float* tWhh,
                       const float* dWhh, float* d0, float* d1, float* d2,
                       float* d3, __hip_bfloat16* p0, __hip_bfloat16* p1,
                       __hip_bfloat16* p2) {
    int which = blockIdx.y;
    if (which < 4) {
        const float* s;
        float* d;
        int N, K;
        switch (which) {
            case 0: s = eWih; d = d0; N = H3; K = H; break;
            case 1: s = tWih; d = d1; N = H3; K = H; break;
            case 2: s = dWih; d = d2; N = H3; K = H; break;
            default: s = projW; d = d3; N = H; K = 2 * H; break;
        }
        int n = blockIdx.x;
        if (n >= N) return;
        for (int k = threadIdx.x; k < K; k += 256)
            d[(size_t)(k >> 2) * (N * 4) + n * 4 + (k & 3)] = s[(size_t)n * K + k];
    } else {
        if (blockIdx.x >= 96) return;
        const float* s = which == 4 ? eWhh : (which == 5 ? tWhh : dWhh);
        __hip_bfloat16* d = which == 4 ? p0 : (which == 5 ? p1 : p2);
        int idx = blockIdx.x * 256 + threadIdx.x;  // 0..24575
        int lane = idx & 63;
        int f = (idx >> 6) % 48;
        int w = idx / (48 * 64);
        int ks = f / 6, nt = f % 6;
        int row = ((nt >> 1) << 8) + (w << 5) + ((nt & 1) << 4) + (lane & 15);
        int k = (ks << 5) + ((lane >> 4) << 3);
#pragma unroll
        for (int j = 0; j < 8; ++j)
            d[(size_t)idx * 8 + j] = __float2bfloat16(s[(size_t)row * H + k + j]);
    }
}

// ---------------- gi = emb[toks] @ Wih^T + bih (+bhh r,z)  [+ outW cvt] ----
__global__ __launch_bounds__(256) void k_gi_cvt(
    const int* in_toks, const int* tag_toks, const int* tgt_toks,
    const float* enc_emb, const float* tag_emb, const float* W4e,
    const float* W4t, const float* W4d, const float* bih_e, const float* bhh_e,
    const float* bih_t, const float* bhh_t, const float* bih_d,
    const float* bhh_d, float* gi_e, float* gi_t, float* gi_d,
    const float* outW, __hip_bfloat16* outWb) {
    int bx = blockIdx.x, tid = threadIdx.x;
    if (bx >= NGI) {
        int i4 = ((bx - NGI) * 256 + tid) * 4;
        if (i4 >= VP * H) return;
        int row = i4 >> 8;
        float4 v;
        if (row < VSZ) v = *(const float4*)(outW + i4);
        else v = make_float4(0.f, 0.f, 0.f, 0.f);
        outWb[i4 + 0] = __float2bfloat16(v.x);
        outWb[i4 + 1] = __float2bfloat16(v.y);
        outWb[i4 + 2] = __float2bfloat16(v.z);
        outWb[i4 + 3] = __float2bfloat16(v.w);
        return;
    }
    __shared__ float x[NBATCH][H];
    int g = bx % 3, tt = bx / 3;
    const int* toks;
    const float* emb;
    const float* W4;
    const float* bihp;
    const float* bhhp;
    float* gip;
    int t, mode;
    if (tt < TIN) {
        toks = in_toks; emb = enc_emb; W4 = W4e; bihp = bih_e; bhhp = bhh_e;
        gip = gi_e; t = tt; mode = 0;
    } else if (tt < TIN + TTAG) {
        toks = tag_toks; emb = tag_emb; W4 = W4t; bihp = bih_t; bhhp = bhh_t;
        gip = gi_t; t = tt - TIN; mode = 0;
    } else {
        toks = tgt_toks; emb = enc_emb; W4 = W4d; bihp = bih_d; bhhp = bhh_d;
        gip = gi_d; t = tt - TIN - TTAG; mode = 2;
    }
    for (int b = 0; b < NBATCH; ++b) {
        int tok;
        if (mode == 2) tok = (t == 0) ? 1 : toks[(t - 1) * NBATCH + b];
        else tok = toks[t * NBATCH + b];
        float v = emb[(size_t)tok * H + tid];
        if (mode == 2) v = fmaxf(v, 0.0f);
        x[b][tid] = v;
    }
    __syncthreads();
    int nb_ = tid & 63, mg = tid >> 6;
    float acc[4][8];
#pragma unroll
    for (int j = 0; j < 4; ++j)
#pragma unroll
        for (int mi = 0; mi < 8; ++mi) acc[j][mi] = 0.f;
    for (int k4 = 0; k4 < 64; ++k4) {
        const float4* wrow = (const float4*)(W4 + (size_t)k4 * 3072);
        float4 w0 = wrow[g * 256 + nb_];
        float4 w1 = wrow[g * 256 + nb_ + 64];
        float4 w2 = wrow[g * 256 + nb_ + 128];
        float4 w3 = wrow[g * 256 + nb_ + 192];
#pragma unroll
        for (int mi = 0; mi < 8; ++mi) {
            float4 xv = *(const float4*)&x[mg * 8 + mi][k4 * 4];
            acc[0][mi] += dot4(xv, w0);
            acc[1][mi] += dot4(xv, w1);
            acc[2][mi] += dot4(xv, w2);
            acc[3][mi] += dot4(xv, w3);
        }
    }
#pragma unroll
    for (int j = 0; j < 4; ++j) {
        int n = g * 256 + nb_ + j * 64;
        float bv = bihp[n] + (g < 2 ? bhhp[n] : 0.0f);
#pragma unroll
        for (int mi = 0; mi < 8; ++mi) {
            int m = t * NBATCH + mg * 8 + mi;
            gip[(size_t)m * H3 + n] = acc[j][mi] + bv;
        }
    }
}

// ---------------- batch-split GRU scan (no inter-block sync) ---------------
// 512 threads = 8 waves, block owns 16 batch rows.  Whh in registers
// (48 frags = 192 VGPR/wave).  bf16 h in LDS is the master state.
__global__ __launch_bounds__(512, 1) void k_scan(
    int nset1,
    const float* gi1, const __hip_bfloat16* W1, const float* bhh1,
    const float* h01, float* hT1, __hip_bfloat16* out1, int T1,
    const float* gi2, const __hip_bfloat16* W2, const float* bhh2,
    const float* h02, float* hT2, __hip_bfloat16* out2, int T2) {
    __shared__ uint4 HBF[512];     // 8KB bf16 h, XOR-swizzled
    __shared__ float Cc[16][772];  // 48.25KB f32 gate preacts

    int blk = blockIdx.x, tid = threadIdx.x;
    const float *gi, *bhh, *h0;
    const __hip_bfloat16* Wg;
    float* hTp;
    __hip_bfloat16* outp;
    int T, loc;
    if (blk < nset1) {
        gi = gi1; Wg = W1; bhh = bhh1; h0 = h01; hTp = hT1; outp = out1;
        T = T1; loc = blk;
    } else {
        gi = gi2; Wg = W2; bhh = bhh2; h0 = h02; hTp = hT2; outp = out2;
        T = T2; loc = blk - nset1;
    }
    int mb = loc * 16;
    int w = tid >> 6, lane = tid & 63, lr = lane & 15, lg = lane >> 4;
    int lb = tid >> 5, ch = tid & 31, c0 = ch * 8, b = mb + lb;

    // this wave's 48 weight fragments (192 VGPRs)
    short8 wreg[48];
    const uint4* Wg4 = (const uint4*)Wg;
#pragma unroll
    for (int f = 0; f < 48; ++f) {
        uint4 v = Wg4[(size_t)(w * 48 + f) * 64 + lane];
        wreg[f] = *(short8*)&v;
    }
    float bnv0 = bhh[512 + (w << 5) + lr];
    float bnv1 = bhh[512 + (w << 5) + 16 + lr];

    // init h in LDS (bf16 master)
    {
        short8 hb;
        if (h0) {
            float hv[8];
            *(float4*)&hv[0] = *(const float4*)(h0 + (size_t)b * H + c0);
            *(float4*)&hv[4] = *(const float4*)(h0 + (size_t)b * H + c0 + 4);
#pragma unroll
            for (int i = 0; i < 8; ++i) {
                __hip_bfloat16 q = __float2bfloat16(hv[i]);
                hb[i] = *(short*)&q;
            }
        } else {
#pragma unroll
            for (int i = 0; i < 8; ++i) hb[i] = 0;
        }
        ((short8*)HBF)[lb * 32 + (ch ^ (lb & 7))] = hb;
    }
    __syncthreads();

    const short8* HS = (const short8*)HBF;
    for (int t = 0; t < T; ++t) {
        // ---- MFMA: C[16x768] = h @ Whh^T, two 3-acc halves ----
#pragma unroll
        for (int half = 0; half < 2; ++half) {
            f32x4 acc[3];
#pragma unroll
            for (int q = 0; q < 3; ++q) {
                int nt = half * 3 + q;
                float iv = (nt == 4) ? bnv0 : ((nt == 5) ? bnv1 : 0.0f);
                acc[q] = (f32x4){iv, iv, iv, iv};
            }
#pragma unroll
            for (int ks = 0; ks < 8; ++ks) {
                short8 a = HS[lr * 32 + ((ks * 4 + lg) ^ (lr & 7))];
#pragma unroll
                for (int q = 0; q < 3; ++q)
                    acc[q] = __builtin_amdgcn_mfma_f32_16x16x32_bf16(
                        a, wreg[ks * 6 + half * 3 + q], acc[q], 0, 0, 0);
            }
#pragma unroll
            for (int q = 0; q < 3; ++q) {
                int nt = half * 3 + q;
                int col = ((nt >> 1) << 8) + (w << 5) + ((nt & 1) << 4) + lr;
#pragma unroll
                for (int reg = 0; reg < 4; ++reg)
                    Cc[lg * 4 + reg][col] = acc[q][reg];
            }
        }
        bar_lgkm();

        // ---- pointwise: 8 h-elements per thread, gates sequentially ----
        const float* girow = gi + (size_t)(t * NBATCH + b) * H3 + c0;
        short8 hOld = HS[lb * 32 + (ch ^ (lb & 7))];
        float rr[8], zz[8], hn[8];
        {   // r gate
            float4 ca = *(const float4*)&Cc[lb][c0];
            float4 cb = *(const float4*)&Cc[lb][c0 + 4];
            float4 ga = *(const float4*)(girow);
            float4 gb = *(const float4*)(girow + 4);
            rr[0] = 1.0f / (1.0f + __expf(-(ga.x + ca.x)));
            rr[1] = 1.0f / (1.0f + __expf(-(ga.y + ca.y)));
            rr[2] = 1.0f / (1.0f + __expf(-(ga.z + ca.z)));
            rr[3] = 1.0f / (1.0f + __expf(-(ga.w + ca.w)));
            rr[4] = 1.0f / (1.0f + __expf(-(gb.x + cb.x)));
            rr[5] = 1.0f / (1.0f + __expf(-(gb.y + cb.y)));
            rr[6] = 1.0f / (1.0f + __expf(-(gb.z + cb.z)));
            rr[7] = 1.0f / (1.0f + __expf(-(gb.w + cb.w)));
        }
        {   // z gate
            float4 ca = *(const float4*)&Cc[lb][256 + c0];
            float4 cb = *(const float4*)&Cc[lb][256 + c0 + 4];
            float4 ga = *(const float4*)(girow + 256);
            float4 gb = *(const float4*)(girow + 260);
            zz[0] = 1.0f / (1.0f + __expf(-(ga.x + ca.x)));
            zz[1] = 1.0f / (1.0f + __expf(-(ga.y + ca.y)));
            zz[2] = 1.0f / (1.0f + __expf(-(ga.z + ca.z)));
            zz[3] = 1.0f / (1.0f + __expf(-(ga.w + ca.w)));
            zz[4] = 1.0f / (1.0f + __expf(-(gb.x + cb.x)));
            zz[5] = 1.0f / (1.0f + __expf(-(gb.y + cb.y)));
            zz[6] = 1.0f / (1.0f + __expf(-(gb.z + cb.z)));
            zz[7] = 1.0f / (1.0f + __expf(-(gb.w + cb.w)));
        }
        {   // n gate + combine
            float4 ca = *(const float4*)&Cc[lb][512 + c0];
            float4 cb = *(const float4*)&Cc[lb][512 + c0 + 4];
            float4 ga = *(const float4*)(girow + 512);
            float4 gb = *(const float4*)(girow + 516);
            float cn[8], gn[8];
            *(float4*)&cn[0] = ca; *(float4*)&cn[4] = cb;
            *(float4*)&gn[0] = ga; *(float4*)&gn[4] = gb;
#pragma unroll
            for (int i = 0; i < 8; ++i) {
                float xx = gn[i] + rr[i] * cn[i];
                float e2 = __expf(-2.0f * fabsf(xx));
                float nv = copysignf((1.0f - e2) / (1.0f + e2), xx);
                hn[i] = (1.0f - zz[i]) * nv + zz[i] * bf2f(hOld[i]);
            }
        }
        short8 hb;
#pragma unroll
        for (int i = 0; i < 8; ++i) {
            __hip_bfloat16 q = __float2bfloat16(hn[i]);
            hb[i] = *(short*)&q;
        }
        ((short8*)HBF)[lb * 32 + (ch ^ (lb & 7))] = hb;
        if (outp)
            *(short8*)(outp + (size_t)(t * NBATCH + b) * H + c0) = hb;
        if (hTp && t == T - 1) {
            *(float4*)(hTp + (size_t)b * H + c0) = *(float4*)&hn[0];
            *(float4*)(hTp + (size_t)b * H + c0 + 4) = *(float4*)&hn[4];
        }
        bar_lgkm();
    }
}

// ---------------- merged = concat(tag_h, enc_h) @ proj_W^T + proj_b --------
__global__ void k_proj(const float* tag_h, const float* enc_h,
                       const float* W4p, const float* pb, float* merged) {
    __shared__ float c[2 * H];
    int b = blockIdx.x, tid = threadIdx.x;
    c[tid] = tag_h[b * H + tid];
    c[H + tid] = enc_h[b * H + tid];
    __syncthreads();
    float acc = 0.f;
#pragma unroll 4
    for (int k4 = 0; k4 < 128; ++k4) {
        float4 cv = *(const float4*)&c[k4 * 4];
        float4 wv = ((const float4*)(W4p + (size_t)k4 * 1024))[tid];
        acc += dot4(cv, wv);
    }
    merged[b * H + tid] = acc + pb[tid];
}

// ---------------- logits GEMM: C[1280][50003] = A @ Bw^T + bias ------------
__global__ __launch_bounds__(256) void k_logits(const __hip_bfloat16* A,
                                                const __hip_bfloat16* Bw,
                                                const float* bias, float* dout,
                                                float* pmax, float* psum) {
    __shared__ uint4 bsm[2048];       // 32KB B tile
    __shared__ float cst[4][16][68];  // 17KB per-wave C staging
    int bid = blockIdx.x;
    int wg = (bid & 7) * 1955 + (bid >> 3);  // XCD-aware bijective swizzle
    int nblk = wg / 20, mblk = wg % 20;      // N-major: 20 M-tiles per B-tile
    int m0 = mblk * 64, n0 = nblk * 64;
    int tid = threadIdx.x;
    int wave = tid >> 6, lane = tid & 63, lr = lane & 15, lg = lane >> 4;
    const uint4* Bg = (const uint4*)(Bw + (size_t)n0 * H);
#pragma unroll
    for (int i = 0; i < 8; ++i) {
        int c = tid + i * 256;
        int r = c >> 5, g = c & 31;
        bsm[(r << 5) | (g ^ (r & 7))] = Bg[c];
    }
    short8 areg[8];
    const uint4* Ar = (const uint4*)(A + (size_t)(m0 + wave * 16 + lr) * H);
#pragma unroll
    for (int ks = 0; ks < 8; ++ks) {
        uint4 v = Ar[ks * 4 + lg];
        areg[ks] = *(short8*)&v;
    }
    float biasv[4];
    bool valid[4];
#pragma unroll
    for (int ns = 0; ns < 4; ++ns) {
        int n = n0 + ns * 16 + lr;
        valid[ns] = (n < VSZ);
        biasv[ns] = valid[ns] ? bias[n] : 0.f;
    }
    __syncthreads();
    f32x4 acc[4];
#pragma unroll
    for (int ns = 0; ns < 4; ++ns) acc[ns] = (f32x4){0.f, 0.f, 0.f, 0.f};
    const short8* L = (const short8*)bsm;
#pragma unroll
    for (int ks = 0; ks < 8; ++ks) {
        int ga = ks * 4 + lg;
#pragma unroll
        for (int ns = 0; ns < 4; ++ns) {
            int rb = ns * 16 + lr;
            acc[ns] = __builtin_amdgcn_mfma_f32_16x16x32_bf16(
                areg[ks], L[(rb << 5) | (ga ^ (rb & 7))], acc[ns], 0, 0, 0);
        }
    }
    float* cw = &cst[wave][0][0];
#pragma unroll
    for (int reg = 0; reg < 4; ++reg) {
        int m = m0 + wave * 16 + lg * 4 + reg;
        float v[4];
        float rm = -INFINITY;
#pragma unroll
        for (int ns = 0; ns < 4; ++ns) {
            v[ns] = acc[ns][reg] + biasv[ns];
            if (valid[ns]) rm = fmaxf(rm, v[ns]);
            cw[(lg * 4 + reg) * 68 + ns * 16 + lr] = v[ns];
        }
        for (int off = 1; off < 16; off <<= 1) rm = fmaxf(rm, __shfl_xor(rm, off));
        float se = 0.f;
#pragma unroll
        for (int ns = 0; ns < 4; ++ns)
            if (valid[ns]) se += __expf(v[ns] - rm);
        for (int off = 1; off < 16; off <<= 1) se += __shfl_xor(se, off);
        if (lr == 0) {
            pmax[(size_t)m * NT + nblk] = rm;
            psum[(size_t)m * NT + nblk] = se;
        }
    }
    float* dbase = dout + 2 + (size_t)(m0 + wave * 16) * VSZ + n0;
    bool colok = (n0 + lane < VSZ);
#pragma unroll
    for (int rl = 0; rl < 16; ++rl) {
        float val = cst[wave][rl][lane];
        if (colok) dbase[(size_t)rl * VSZ + lane] = val;
    }
}

// ---------------- per-row logsumexp from tile partials ---------------------
__global__ void k_lse(const float* pmax, const float* psum, float* lse) {
    int m = blockIdx.x, tid = threadIdx.x;
    __shared__ float sm[4];
    float lm = -INFINITY;
    for (int i = tid; i < NT; i += 256) lm = fmaxf(lm, pmax[(size_t)m * NT + i]);
    for (int off = 1; off < 64; off <<= 1) lm = fmaxf(lm, __shfl_xor(lm, off));
    if ((tid & 63) == 0) sm[tid >> 6] = lm;
    __syncthreads();
    float M = fmaxf(fmaxf(sm[0], sm[1]), fmaxf(sm[2], sm[3]));
    __syncthreads();
    float s = 0.f;
    for (int i = tid; i < NT; i += 256)
        s += psum[(size_t)m * NT + i] * __expf(pmax[(size_t)m * NT + i] - M);
    for (int off = 1; off < 64; off <<= 1) s += __shfl_xor(s, off);
    if ((tid & 63) == 0) sm[tid >> 6] = s;
    __syncthreads();
    if (tid == 0) lse[m] = M + logf(sm[0] + sm[1] + sm[2] + sm[3]);
}

// ---------------- final NLL loss -------------------------------------------
__global__ void k_loss(const float* lse, const int* tgt, float* dout) {
    int tid = threadIdx.x;
    __shared__ float sm[4];
    float s = 0.f;
    for (int m = tid; m < MT; m += 256) {
        int tg = tgt[m];
        s += lse[m] - dout[2 + (size_t)m * VSZ + tg];
    }
    for (int off = 1; off < 64; off <<= 1) s += __shfl_xor(s, off);
    if ((tid & 63) == 0) sm[tid >> 6] = s;
    __syncthreads();
    if (tid == 0) {
        float total = sm[0] + sm[1] + sm[2] + sm[3];
        dout[0] = total / 32.0f;    // sum over t of mean over batch
        dout[1] = total / 1280.0f;  // / T_tgt
    }
}

// ---------------------------------------------------------------------------
extern "C" void kernel_launch(void* const* d_in, const int* in_sizes, int n_in,
                              void* d_out, int out_size, void* d_ws,
                              size_t ws_size, hipStream_t stream) {
    const int* input_tensor = (const int*)d_in[0];
    const int* target_tensor = (const int*)d_in[1];
    const int* tag_tensor = (const int*)d_in[2];
    const float* enc_emb = (const float*)d_in[3];
    const float* enc_Wih = (const float*)d_in[4];
    const float* enc_Whh = (const float*)d_in[5];
    const float* enc_bih = (const float*)d_in[6];
    const float* enc_bhh = (const float*)d_in[7];
    const float* tag_emb = (const float*)d_in[8];
    const float* tag_Wih = (const float*)d_in[9];
    const float* tag_Whh = (const float*)d_in[10];
    const float* tag_bih = (const float*)d_in[11];
    const float* tag_bhh = (const float*)d_in[12];
    const float* proj_W = (const float*)d_in[13];
    const float* proj_b = (const float*)d_in[14];
    const float* dec_Wih = (const float*)d_in[15];
    const float* dec_Whh = (const float*)d_in[16];
    const float* dec_bih = (const float*)d_in[17];
    const float* dec_bhh = (const float*)d_in[18];
    const float* out_W = (const float*)d_in[19];
    const float* out_b = (const float*)d_in[20];

    char* wsb = (char*)d_ws;
    size_t o = 0;
    auto alloc = [&](size_t bytes) {
        size_t r = o;
        o += (bytes + 511) & ~(size_t)511;
        return r;
    };
    float* W4_enc_ih = (float*)(wsb + alloc(H3 * H * 4));
    float* W4_tag_ih = (float*)(wsb + alloc(H3 * H * 4));
    float* W4_dec_ih = (float*)(wsb + alloc(H3 * H * 4));
    float* W4_proj   = (float*)(wsb + alloc(H * 2 * H * 4));
    float* gi_enc = (float*)(wsb + alloc((size_t)TIN * NBATCH * H3 * 4));
    float* gi_tag = (float*)(wsb + alloc((size_t)TTAG * NBATCH * H3 * 4));
    float* gi_dec = (float*)(wsb + alloc((size_t)TTGT * NBATCH * H3 * 4));
    float* enc_h  = (float*)(wsb + alloc(NBATCH * H * 4));
    float* tag_h  = (float*)(wsb + alloc(NBATCH * H * 4));
    float* merged = (float*)(wsb + alloc(NBATCH * H * 4));
    float* lse    = (float*)(wsb + alloc(MT * 4));
    __hip_bfloat16* Wp_enc = (__hip_bfloat16*)(wsb + alloc(H3 * H * 2));
    __hip_bfloat16* Wp_tag = (__hip_bfloat16*)(wsb + alloc(H3 * H * 2));
    __hip_bfloat16* Wp_dec = (__hip_bfloat16*)(wsb + alloc(H3 * H * 2));
    __hip_bfloat16* outWb  = (__hip_bfloat16*)(wsb + alloc((size_t)VP * H * 2));
    __hip_bfloat16* decA   = (__hip_bfloat16*)(wsb + alloc((size_t)MT * H * 2));
    float* pmax = (float*)(wsb + alloc((size_t)MT * NT * 4));
    float* psum = (float*)(wsb + alloc((size_t)MT * NT * 4));

    float* dout = (float*)d_out;

    // 1) prep: Wih/proj transposes + Whh->fragment bf16
    k_prep<<<dim3(H3, 7), 256, 0, stream>>>(
        enc_Wih, tag_Wih, dec_Wih, proj_W, enc_Whh, tag_Whh, dec_Whh,
        W4_enc_ih, W4_tag_ih, W4_dec_ih, W4_proj, Wp_enc, Wp_tag, Wp_dec);

    // 2) gi precompute (3 GRUs) + out_W->bf16, one launch
    k_gi_cvt<<<NGI + NCVT, 256, 0, stream>>>(
        input_tensor, tag_tensor, target_tensor, enc_emb, tag_emb, W4_enc_ih,
        W4_tag_ih, W4_dec_ih, enc_bih, enc_bhh, tag_bih, tag_bhh, dec_bih,
        dec_bhh, gi_enc, gi_tag, gi_dec, out_W, outWb);

    // 3) encoder + tag GRU scans (4 independent blocks)
    k_scan<<<4, 512, 0, stream>>>(
        2, gi_enc, Wp_enc, enc_bhh, nullptr, enc_h, nullptr, TIN,
        gi_tag, Wp_tag, tag_bhh, nullptr, tag_h, nullptr, TTAG);

    // 4) proj -> merged
    k_proj<<<NBATCH, 256, 0, stream>>>(tag_h, enc_h, W4_proj, proj_b, merged);

    // 5) decoder GRU scan (writes bf16 A matrix)
    k_scan<<<2, 512, 0, stream>>>(
        2, gi_dec, Wp_dec, dec_bhh, merged, nullptr, decA, TTGT,
        nullptr, nullptr, nullptr, nullptr, nullptr, nullptr, 0);

    // 6) logits GEMM + LSE partials (grid = 782*20)
    k_logits<<<NT * 20, 256, 0, stream>>>(decA, outWb, out_b, dout, pmax, psum);

    // 7) per-row logsumexp
    k_lse<<<MT, 256, 0, stream>>>(pmax, psum, lse);

    // 8) loss scalars
    k_loss<<<1, 256, 0, stream>>>(lse, target_tensor, dout);
}

// Round 7
// 497.107 us; speedup vs baseline: 1.8699x; 1.0561x over previous
//
#include <hip/hip_runtime.h>
#include <hip/hip_bf16.h>
#include <math.h>

// ---------------------------------------------------------------------------
// Seq2Seq: enc GRU (T=50) + tag GRU (T=20) -> proj -> dec GRU (T=40)
//          -> logits GEMM (1280x50003, K=256, bf16 MFMA) -> LSE -> NLL loss
//
// Round 7: kill the k_scan VGPR spill for real + hide gi latency.
//   Round-6 evidence: VGPR_Count=128 because LDS 57.8KB allows 2 blocks/CU,
//   so the backend caps VGPRs at 2048/16=128 and spills wreg[48] to scratch
//   (L2 -> invisible in FETCH_SIZE, but ~48 reloads/step on critical path).
//   Fix: LDS 152.25KB (adds 2x48KB gi staging dbuf) -> 1 block/CU -> 256
//   VGPR budget -> wreg stays in registers.  gi(t+1) staged into LDS via
//   global_load_lds (width 16) during pointwise(t); each wave stages exactly
//   the 2 batch rows it reads, so per-wave vmcnt(0) suffices (no barrier
//   needed for the staging itself).
// ---------------------------------------------------------------------------

#define H 256
#define H3 768
#define NBATCH 32
#define TIN 50
#define TTGT 40
#define TTAG 20
#define VSZ 50003
#define VP 50048          // padded to 64
#define NT 782            // VP / 64
#define MT 1280           // TTGT * NBATCH
#define NGI 330           // 110 timesteps * 3 gates
#define NCVT 12512        // VP*H/4/256

typedef float f32x4 __attribute__((ext_vector_type(4)));
typedef short short8 __attribute__((ext_vector_type(8)));
typedef const __attribute__((address_space(1))) unsigned int* gas_t;
typedef __attribute__((address_space(3))) unsigned int* las_t;

__device__ __forceinline__ float dot4(float4 a, float4 b) {
    return a.x * b.x + a.y * b.y + a.z * b.z + a.w * b.w;
}

__device__ __forceinline__ float bf2f(short s) {
    unsigned int u = ((unsigned int)(unsigned short)s) << 16;
    return __builtin_bit_cast(float, u);
}

// barrier with LDS-only drain: leaves global ops in flight
__device__ __forceinline__ void bar_lgkm() {
    asm volatile("s_waitcnt lgkmcnt(0)" ::: "memory");
    __builtin_amdgcn_s_barrier();
    __builtin_amdgcn_sched_barrier(0);
}

// ---------------- prep: Wih/proj transpose + Whh -> MFMA-B fragments -------
// grid (768, 7): y<4 transpose to [(k/4)][N][4]; y>=4 prep_w (x<96 active)
__global__ void k_prep(const float* eWih, const float* tWih, const float* dWih,
                       const float* projW, const float* eWhh, const float* tWhh,
                       const float* dWhh, float* d0, float* d1, float* d2,
                       float* d3, __hip_bfloat16* p0, __hip_bfloat16* p1,
                       __hip_bfloat16* p2) {
    int which = blockIdx.y;
    if (which < 4) {
        const float* s;
        float* d;
        int N, K;
        switch (which) {
            case 0: s = eWih; d = d0; N = H3; K = H; break;
            case 1: s = tWih; d = d1; N = H3; K = H; break;
            case 2: s = dWih; d = d2; N = H3; K = H; break;
            default: s = projW; d = d3; N = H; K = 2 * H; break;
        }
        int n = blockIdx.x;
        if (n >= N) return;
        for (int k = threadIdx.x; k < K; k += 256)
            d[(size_t)(k >> 2) * (N * 4) + n * 4 + (k & 3)] = s[(size_t)n * K + k];
    } else {
        if (blockIdx.x >= 96) return;
        const float* s = which == 4 ? eWhh : (which == 5 ? tWhh : dWhh);
        __hip_bfloat16* d = which == 4 ? p0 : (which == 5 ? p1 : p2);
        int idx = blockIdx.x * 256 + threadIdx.x;  // 0..24575
        int lane = idx & 63;
        int f = (idx >> 6) % 48;
        int w = idx / (48 * 64);
        int ks = f / 6, nt = f % 6;
        int row = ((nt >> 1) << 8) + (w << 5) + ((nt & 1) << 4) + (lane & 15);
        int k = (ks << 5) + ((lane >> 4) << 3);
#pragma unroll
        for (int j = 0; j < 8; ++j)
            d[(size_t)idx * 8 + j] = __float2bfloat16(s[(size_t)row * H + k + j]);
    }
}

// ---------------- gi = emb[toks] @ Wih^T + bih (+bhh r,z)  [+ outW cvt] ----
__global__ __launch_bounds__(256) void k_gi_cvt(
    const int* in_toks, const int* tag_toks, const int* tgt_toks,
    const float* enc_emb, const float* tag_emb, const float* W4e,
    const float* W4t, const float* W4d, const float* bih_e, const float* bhh_e,
    const float* bih_t, const float* bhh_t, const float* bih_d,
    const float* bhh_d, float* gi_e, float* gi_t, float* gi_d,
    const float* outW, __hip_bfloat16* outWb) {
    int bx = blockIdx.x, tid = threadIdx.x;
    if (bx >= NGI) {
        int i4 = ((bx - NGI) * 256 + tid) * 4;
        if (i4 >= VP * H) return;
        int row = i4 >> 8;
        float4 v;
        if (row < VSZ) v = *(const float4*)(outW + i4);
        else v = make_float4(0.f, 0.f, 0.f, 0.f);
        outWb[i4 + 0] = __float2bfloat16(v.x);
        outWb[i4 + 1] = __float2bfloat16(v.y);
        outWb[i4 + 2] = __float2bfloat16(v.z);
        outWb[i4 + 3] = __float2bfloat16(v.w);
        return;
    }
    __shared__ float x[NBATCH][H];
    int g = bx % 3, tt = bx / 3;
    const int* toks;
    const float* emb;
    const float* W4;
    const float* bihp;
    const float* bhhp;
    float* gip;
    int t, mode;
    if (tt < TIN) {
        toks = in_toks; emb = enc_emb; W4 = W4e; bihp = bih_e; bhhp = bhh_e;
        gip = gi_e; t = tt; mode = 0;
    } else if (tt < TIN + TTAG) {
        toks = tag_toks; emb = tag_emb; W4 = W4t; bihp = bih_t; bhhp = bhh_t;
        gip = gi_t; t = tt - TIN; mode = 0;
    } else {
        toks = tgt_toks; emb = enc_emb; W4 = W4d; bihp = bih_d; bhhp = bhh_d;
        gip = gi_d; t = tt - TIN - TTAG; mode = 2;
    }
    for (int b = 0; b < NBATCH; ++b) {
        int tok;
        if (mode == 2) tok = (t == 0) ? 1 : toks[(t - 1) * NBATCH + b];
        else tok = toks[t * NBATCH + b];
        float v = emb[(size_t)tok * H + tid];
        if (mode == 2) v = fmaxf(v, 0.0f);
        x[b][tid] = v;
    }
    __syncthreads();
    int nb_ = tid & 63, mg = tid >> 6;
    float acc[4][8];
#pragma unroll
    for (int j = 0; j < 4; ++j)
#pragma unroll
        for (int mi = 0; mi < 8; ++mi) acc[j][mi] = 0.f;
    for (int k4 = 0; k4 < 64; ++k4) {
        const float4* wrow = (const float4*)(W4 + (size_t)k4 * 3072);
        float4 w0 = wrow[g * 256 + nb_];
        float4 w1 = wrow[g * 256 + nb_ + 64];
        float4 w2 = wrow[g * 256 + nb_ + 128];
        float4 w3 = wrow[g * 256 + nb_ + 192];
#pragma unroll
        for (int mi = 0; mi < 8; ++mi) {
            float4 xv = *(const float4*)&x[mg * 8 + mi][k4 * 4];
            acc[0][mi] += dot4(xv, w0);
            acc[1][mi] += dot4(xv, w1);
            acc[2][mi] += dot4(xv, w2);
            acc[3][mi] += dot4(xv, w3);
        }
    }
#pragma unroll
    for (int j = 0; j < 4; ++j) {
        int n = g * 256 + nb_ + j * 64;
        float bv = bihp[n] + (g < 2 ? bhhp[n] : 0.0f);
#pragma unroll
        for (int mi = 0; mi < 8; ++mi) {
            int m = t * NBATCH + mg * 8 + mi;
            gip[(size_t)m * H3 + n] = acc[j][mi] + bv;
        }
    }
}

// ---------------- batch-split GRU scan (no inter-block sync) ---------------
// 512 threads = 8 waves, block owns 16 batch rows.  Whh in registers
// (48 frags = 192 VGPR/wave).  bf16 h in LDS master.  gi double-buffered in
// LDS via global_load_lds (wave stages exactly the rows it reads).
// LDS 152.25KB -> 1 block/CU -> VGPR budget 256 -> no wreg spill.
__global__ __launch_bounds__(512, 1) void k_scan(
    int nset1,
    const float* gi1, const __hip_bfloat16* W1, const float* bhh1,
    const float* h01, float* hT1, __hip_bfloat16* out1, int T1,
    const float* gi2, const __hip_bfloat16* W2, const float* bhh2,
    const float* h02, float* hT2, __hip_bfloat16* out2, int T2) {
    __shared__ uint4 HBF[512];        // 8KB bf16 h, XOR-swizzled
    __shared__ float Cc[16][772];     // 48.25KB f32 gate preacts
    __shared__ float GI[2][12288];    // 96KB gi double-buffer (16 rows x 768)

    int blk = blockIdx.x, tid = threadIdx.x;
    const float *gi, *bhh, *h0;
    const __hip_bfloat16* Wg;
    float* hTp;
    __hip_bfloat16* outp;
    int T, loc;
    if (blk < nset1) {
        gi = gi1; Wg = W1; bhh = bhh1; h0 = h01; hTp = hT1; outp = out1;
        T = T1; loc = blk;
    } else {
        gi = gi2; Wg = W2; bhh = bhh2; h0 = h02; hTp = hT2; outp = out2;
        T = T2; loc = blk - nset1;
    }
    int mb = loc * 16;
    int w = tid >> 6, lane = tid & 63, lr = lane & 15, lg = lane >> 4;
    int lb = tid >> 5, ch = tid & 31, c0 = ch * 8, b = mb + lb;

    // this wave's 48 weight fragments (192 VGPRs)
    short8 wreg[48];
    const uint4* Wg4 = (const uint4*)Wg;
#pragma unroll
    for (int f = 0; f < 48; ++f) {
        uint4 v = Wg4[(size_t)(w * 48 + f) * 64 + lane];
        wreg[f] = *(short8*)&v;
    }
    float bnv0 = bhh[512 + (w << 5) + lr];
    float bnv1 = bhh[512 + (w << 5) + 16 + lr];

    // init h in LDS (bf16 master)
    {
        short8 hb;
        if (h0) {
            float hv[8];
            *(float4*)&hv[0] = *(const float4*)(h0 + (size_t)b * H + c0);
            *(float4*)&hv[4] = *(const float4*)(h0 + (size_t)b * H + c0 + 4);
#pragma unroll
            for (int i = 0; i < 8; ++i) {
                __hip_bfloat16 q = __float2bfloat16(hv[i]);
                hb[i] = *(short*)&q;
            }
        } else {
#pragma unroll
            for (int i = 0; i < 8; ++i) hb[i] = 0;
        }
        ((short8*)HBF)[lb * 32 + (ch ^ (lb & 7))] = hb;
    }
    // prologue: stage gi(0) into GI[0] (wave w stages rows 2w..2w+1)
    {
        const float* src = gi + ((size_t)0 * NBATCH + mb) * H3 + w * 1536;
#pragma unroll
        for (int j = 0; j < 6; ++j) {
            const float* g = src + j * 256 + lane * 4;
            float* l = &GI[0][w * 1536 + j * 256];
            __builtin_amdgcn_global_load_lds((gas_t)g, (las_t)l, 16, 0, 0);
        }
    }
    __syncthreads();

    const short8* HS = (const short8*)HBF;
    for (int t = 0; t < T; ++t) {
        // ---- MFMA: C[16x768] = h @ Whh^T, two 3-acc halves ----
#pragma unroll
        for (int half = 0; half < 2; ++half) {
            f32x4 acc[3];
#pragma unroll
            for (int q = 0; q < 3; ++q) {
                int nt = half * 3 + q;
                float iv = (nt == 4) ? bnv0 : ((nt == 5) ? bnv1 : 0.0f);
                acc[q] = (f32x4){iv, iv, iv, iv};
            }
#pragma unroll
            for (int ks = 0; ks < 8; ++ks) {
                short8 a = HS[lr * 32 + ((ks * 4 + lg) ^ (lr & 7))];
#pragma unroll
                for (int q = 0; q < 3; ++q)
                    acc[q] = __builtin_amdgcn_mfma_f32_16x16x32_bf16(
                        a, wreg[ks * 6 + half * 3 + q], acc[q], 0, 0, 0);
            }
#pragma unroll
            for (int q = 0; q < 3; ++q) {
                int nt = half * 3 + q;
                int col = ((nt >> 1) << 8) + (w << 5) + ((nt & 1) << 4) + lr;
#pragma unroll
                for (int reg = 0; reg < 4; ++reg)
                    Cc[lg * 4 + reg][col] = acc[q][reg];
            }
        }
        bar_lgkm();

        // gi(t) staging complete (per-wave: this wave staged its own rows)
        asm volatile("s_waitcnt vmcnt(0)" ::: "memory");
        __builtin_amdgcn_sched_barrier(0);
        // issue stage of gi(t+1): hides under pointwise(t) + MFMA(t+1)
        if (t + 1 < T) {
            const float* src =
                gi + ((size_t)(t + 1) * NBATCH + mb) * H3 + w * 1536;
            float* dstbase = &GI[(t + 1) & 1][w * 1536];
#pragma unroll
            for (int j = 0; j < 6; ++j) {
                const float* g = src + j * 256 + lane * 4;
                float* l = dstbase + j * 256;
                __builtin_amdgcn_global_load_lds((gas_t)g, (las_t)l, 16, 0, 0);
            }
        }

        // ---- pointwise: 8 h-elements per thread, gates sequentially ----
        const float* girow = &GI[t & 1][lb * 768 + c0];
        short8 hOld = HS[lb * 32 + (ch ^ (lb & 7))];
        float rr[8], zz[8], hn[8];
        {   // r gate
            float4 ca = *(const float4*)&Cc[lb][c0];
            float4 cb = *(const float4*)&Cc[lb][c0 + 4];
            float4 ga = *(const float4*)(girow);
            float4 gb = *(const float4*)(girow + 4);
            rr[0] = 1.0f / (1.0f + __expf(-(ga.x + ca.x)));
            rr[1] = 1.0f / (1.0f + __expf(-(ga.y + ca.y)));
            rr[2] = 1.0f / (1.0f + __expf(-(ga.z + ca.z)));
            rr[3] = 1.0f / (1.0f + __expf(-(ga.w + ca.w)));
            rr[4] = 1.0f / (1.0f + __expf(-(gb.x + cb.x)));
            rr[5] = 1.0f / (1.0f + __expf(-(gb.y + cb.y)));
            rr[6] = 1.0f / (1.0f + __expf(-(gb.z + cb.z)));
            rr[7] = 1.0f / (1.0f + __expf(-(gb.w + cb.w)));
        }
        {   // z gate
            float4 ca = *(const float4*)&Cc[lb][256 + c0];
            float4 cb = *(const float4*)&Cc[lb][256 + c0 + 4];
            float4 ga = *(const float4*)(girow + 256);
            float4 gb = *(const float4*)(girow + 260);
            zz[0] = 1.0f / (1.0f + __expf(-(ga.x + ca.x)));
            zz[1] = 1.0f / (1.0f + __expf(-(ga.y + ca.y)));
            zz[2] = 1.0f / (1.0f + __expf(-(ga.z + ca.z)));
            zz[3] = 1.0f / (1.0f + __expf(-(ga.w + ca.w)));
            zz[4] = 1.0f / (1.0f + __expf(-(gb.x + cb.x)));
            zz[5] = 1.0f / (1.0f + __expf(-(gb.y + cb.y)));
            zz[6] = 1.0f / (1.0f + __expf(-(gb.z + cb.z)));
            zz[7] = 1.0f / (1.0f + __expf(-(gb.w + cb.w)));
        }
        {   // n gate + combine
            float4 ca = *(const float4*)&Cc[lb][512 + c0];
            float4 cb = *(const float4*)&Cc[lb][512 + c0 + 4];
            float4 ga = *(const float4*)(girow + 512);
            float4 gb = *(const float4*)(girow + 516);
            float cn[8], gn[8];
            *(float4*)&cn[0] = ca; *(float4*)&cn[4] = cb;
            *(float4*)&gn[0] = ga; *(float4*)&gn[4] = gb;
#pragma unroll
            for (int i = 0; i < 8; ++i) {
                float xx = gn[i] + rr[i] * cn[i];
                float e2 = __expf(-2.0f * fabsf(xx));
                float nv = copysignf((1.0f - e2) / (1.0f + e2), xx);
                hn[i] = (1.0f - zz[i]) * nv + zz[i] * bf2f(hOld[i]);
            }
        }
        short8 hb;
#pragma unroll
        for (int i = 0; i < 8; ++i) {
            __hip_bfloat16 q = __float2bfloat16(hn[i]);
            hb[i] = *(short*)&q;
        }
        ((short8*)HBF)[lb * 32 + (ch ^ (lb & 7))] = hb;
        if (outp)
            *(short8*)(outp + (size_t)(t * NBATCH + b) * H + c0) = hb;
        if (hTp && t == T - 1) {
            *(float4*)(hTp + (size_t)b * H + c0) = *(float4*)&hn[0];
            *(float4*)(hTp + (size_t)b * H + c0 + 4) = *(float4*)&hn[4];
        }
        bar_lgkm();
    }
}

// ---------------- merged = concat(tag_h, enc_h) @ proj_W^T + proj_b --------
__global__ void k_proj(const float* tag_h, const float* enc_h,
                       const float* W4p, const float* pb, float* merged) {
    __shared__ float c[2 * H];
    int b = blockIdx.x, tid = threadIdx.x;
    c[tid] = tag_h[b * H + tid];
    c[H + tid] = enc_h[b * H + tid];
    __syncthreads();
    float acc = 0.f;
#pragma unroll 4
    for (int k4 = 0; k4 < 128; ++k4) {
        float4 cv = *(const float4*)&c[k4 * 4];
        float4 wv = ((const float4*)(W4p + (size_t)k4 * 1024))[tid];
        acc += dot4(cv, wv);
    }
    merged[b * H + tid] = acc + pb[tid];
}

// ---------------- logits GEMM: C[1280][50003] = A @ Bw^T + bias ------------
__global__ __launch_bounds__(256) void k_logits(const __hip_bfloat16* A,
                                                const __hip_bfloat16* Bw,
                                                const float* bias, float* dout,
                                                float* pmax, float* psum) {
    __shared__ uint4 bsm[2048];       // 32KB B tile
    __shared__ float cst[4][16][68];  // 17KB per-wave C staging
    int bid = blockIdx.x;
    int wg = (bid & 7) * 1955 + (bid >> 3);  // XCD-aware bijective swizzle
    int nblk = wg / 20, mblk = wg % 20;      // N-major: 20 M-tiles per B-tile
    int m0 = mblk * 64, n0 = nblk * 64;
    int tid = threadIdx.x;
    int wave = tid >> 6, lane = tid & 63, lr = lane & 15, lg = lane >> 4;
    const uint4* Bg = (const uint4*)(Bw + (size_t)n0 * H);
#pragma unroll
    for (int i = 0; i < 8; ++i) {
        int c = tid + i * 256;
        int r = c >> 5, g = c & 31;
        bsm[(r << 5) | (g ^ (r & 7))] = Bg[c];
    }
    short8 areg[8];
    const uint4* Ar = (const uint4*)(A + (size_t)(m0 + wave * 16 + lr) * H);
#pragma unroll
    for (int ks = 0; ks < 8; ++ks) {
        uint4 v = Ar[ks * 4 + lg];
        areg[ks] = *(short8*)&v;
    }
    float biasv[4];
    bool valid[4];
#pragma unroll
    for (int ns = 0; ns < 4; ++ns) {
        int n = n0 + ns * 16 + lr;
        valid[ns] = (n < VSZ);
        biasv[ns] = valid[ns] ? bias[n] : 0.f;
    }
    __syncthreads();
    f32x4 acc[4];
#pragma unroll
    for (int ns = 0; ns < 4; ++ns) acc[ns] = (f32x4){0.f, 0.f, 0.f, 0.f};
    const short8* L = (const short8*)bsm;
#pragma unroll
    for (int ks = 0; ks < 8; ++ks) {
        int ga = ks * 4 + lg;
#pragma unroll
        for (int ns = 0; ns < 4; ++ns) {
            int rb = ns * 16 + lr;
            acc[ns] = __builtin_amdgcn_mfma_f32_16x16x32_bf16(
                areg[ks], L[(rb << 5) | (ga ^ (rb & 7))], acc[ns], 0, 0, 0);
        }
    }
    float* cw = &cst[wave][0][0];
#pragma unroll
    for (int reg = 0; reg < 4; ++reg) {
        int m = m0 + wave * 16 + lg * 4 + reg;
        float v[4];
        float rm = -INFINITY;
#pragma unroll
        for (int ns = 0; ns < 4; ++ns) {
            v[ns] = acc[ns][reg] + biasv[ns];
            if (valid[ns]) rm = fmaxf(rm, v[ns]);
            cw[(lg * 4 + reg) * 68 + ns * 16 + lr] = v[ns];
        }
        for (int off = 1; off < 16; off <<= 1) rm = fmaxf(rm, __shfl_xor(rm, off));
        float se = 0.f;
#pragma unroll
        for (int ns = 0; ns < 4; ++ns)
            if (valid[ns]) se += __expf(v[ns] - rm);
        for (int off = 1; off < 16; off <<= 1) se += __shfl_xor(se, off);
        if (lr == 0) {
            pmax[(size_t)m * NT + nblk] = rm;
            psum[(size_t)m * NT + nblk] = se;
        }
    }
    float* dbase = dout + 2 + (size_t)(m0 + wave * 16) * VSZ + n0;
    bool colok = (n0 + lane < VSZ);
#pragma unroll
    for (int rl = 0; rl < 16; ++rl) {
        float val = cst[wave][rl][lane];
        if (colok) dbase[(size_t)rl * VSZ + lane] = val;
    }
}

// ---------------- per-row logsumexp from tile partials ---------------------
__global__ void k_lse(const float* pmax, const float* psum, float* lse) {
    int m = blockIdx.x, tid = threadIdx.x;
    __shared__ float sm[4];
    float lm = -INFINITY;
    for (int i = tid; i < NT; i += 256) lm = fmaxf(lm, pmax[(size_t)m * NT + i]);
    for (int off = 1; off < 64; off <<= 1) lm = fmaxf(lm, __shfl_xor(lm, off));
    if ((tid & 63) == 0) sm[tid >> 6] = lm;
    __syncthreads();
    float M = fmaxf(fmaxf(sm[0], sm[1]), fmaxf(sm[2], sm[3]));
    __syncthreads();
    float s = 0.f;
    for (int i = tid; i < NT; i += 256)
        s += psum[(size_t)m * NT + i] * __expf(pmax[(size_t)m * NT + i] - M);
    for (int off = 1; off < 64; off <<= 1) s += __shfl_xor(s, off);
    if ((tid & 63) == 0) sm[tid >> 6] = s;
    __syncthreads();
    if (tid == 0) lse[m] = M + logf(sm[0] + sm[1] + sm[2] + sm[3]);
}

// ---------------- final NLL loss -------------------------------------------
__global__ void k_loss(const float* lse, const int* tgt, float* dout) {
    int tid = threadIdx.x;
    __shared__ float sm[4];
    float s = 0.f;
    for (int m = tid; m < MT; m += 256) {
        int tg = tgt[m];
        s += lse[m] - dout[2 + (size_t)m * VSZ + tg];
    }
    for (int off = 1; off < 64; off <<= 1) s += __shfl_xor(s, off);
    if ((tid & 63) == 0) sm[tid >> 6] = s;
    __syncthreads();
    if (tid == 0) {
        float total = sm[0] + sm[1] + sm[2] + sm[3];
        dout[0] = total / 32.0f;    // sum over t of mean over batch
        dout[1] = total / 1280.0f;  // / T_tgt
    }
}

// ---------------------------------------------------------------------------
extern "C" void kernel_launch(void* const* d_in, const int* in_sizes, int n_in,
                              void* d_out, int out_size, void* d_ws,
                              size_t ws_size, hipStream_t stream) {
    const int* input_tensor = (const int*)d_in[0];
    const int* target_tensor = (const int*)d_in[1];
    const int* tag_tensor = (const int*)d_in[2];
    const float* enc_emb = (const float*)d_in[3];
    const float* enc_Wih = (const float*)d_in[4];
    const float* enc_Whh = (const float*)d_in[5];
    const float* enc_bih = (const float*)d_in[6];
    const float* enc_bhh = (const float*)d_in[7];
    const float* tag_emb = (const float*)d_in[8];
    const float* tag_Wih = (const float*)d_in[9];
    const float* tag_Whh = (const float*)d_in[10];
    const float* tag_bih = (const float*)d_in[11];
    const float* tag_bhh = (const float*)d_in[12];
    const float* proj_W = (const float*)d_in[13];
    const float* proj_b = (const float*)d_in[14];
    const float* dec_Wih = (const float*)d_in[15];
    const float* dec_Whh = (const float*)d_in[16];
    const float* dec_bih = (const float*)d_in[17];
    const float* dec_bhh = (const float*)d_in[18];
    const float* out_W = (const float*)d_in[19];
    const float* out_b = (const float*)d_in[20];

    char* wsb = (char*)d_ws;
    size_t o = 0;
    auto alloc = [&](size_t bytes) {
        size_t r = o;
        o += (bytes + 511) & ~(size_t)511;
        return r;
    };
    float* W4_enc_ih = (float*)(wsb + alloc(H3 * H * 4));
    float* W4_tag_ih = (float*)(wsb + alloc(H3 * H * 4));
    float* W4_dec_ih = (float*)(wsb + alloc(H3 * H * 4));
    float* W4_proj   = (float*)(wsb + alloc(H * 2 * H * 4));
    float* gi_enc = (float*)(wsb + alloc((size_t)TIN * NBATCH * H3 * 4));
    float* gi_tag = (float*)(wsb + alloc((size_t)TTAG * NBATCH * H3 * 4));
    float* gi_dec = (float*)(wsb + alloc((size_t)TTGT * NBATCH * H3 * 4));
    float* enc_h  = (float*)(wsb + alloc(NBATCH * H * 4));
    float* tag_h  = (float*)(wsb + alloc(NBATCH * H * 4));
    float* merged = (float*)(wsb + alloc(NBATCH * H * 4));
    float* lse    = (float*)(wsb + alloc(MT * 4));
    __hip_bfloat16* Wp_enc = (__hip_bfloat16*)(wsb + alloc(H3 * H * 2));
    __hip_bfloat16* Wp_tag = (__hip_bfloat16*)(wsb + alloc(H3 * H * 2));
    __hip_bfloat16* Wp_dec = (__hip_bfloat16*)(wsb + alloc(H3 * H * 2));
    __hip_bfloat16* outWb  = (__hip_bfloat16*)(wsb + alloc((size_t)VP * H * 2));
    __hip_bfloat16* decA   = (__hip_bfloat16*)(wsb + alloc((size_t)MT * H * 2));
    float* pmax = (float*)(wsb + alloc((size_t)MT * NT * 4));
    float* psum = (float*)(wsb + alloc((size_t)MT * NT * 4));

    float* dout = (float*)d_out;

    // 1) prep: Wih/proj transposes + Whh->fragment bf16
    k_prep<<<dim3(H3, 7), 256, 0, stream>>>(
        enc_Wih, tag_Wih, dec_Wih, proj_W, enc_Whh, tag_Whh, dec_Whh,
        W4_enc_ih, W4_tag_ih, W4_dec_ih, W4_proj, Wp_enc, Wp_tag, Wp_dec);

    // 2) gi precompute (3 GRUs) + out_W->bf16, one launch
    k_gi_cvt<<<NGI + NCVT, 256, 0, stream>>>(
        input_tensor, tag_tensor, target_tensor, enc_emb, tag_emb, W4_enc_ih,
        W4_tag_ih, W4_dec_ih, enc_bih, enc_bhh, tag_bih, tag_bhh, dec_bih,
        dec_bhh, gi_enc, gi_tag, gi_dec, out_W, outWb);

    // 3) encoder + tag GRU scans (4 independent blocks)
    k_scan<<<4, 512, 0, stream>>>(
        2, gi_enc, Wp_enc, enc_bhh, nullptr, enc_h, nullptr, TIN,
        gi_tag, Wp_tag, tag_bhh, nullptr, tag_h, nullptr, TTAG);

    // 4) proj -> merged
    k_proj<<<NBATCH, 256, 0, stream>>>(tag_h, enc_h, W4_proj, proj_b, merged);

    // 5) decoder GRU scan (writes bf16 A matrix)
    k_scan<<<2, 512, 0, stream>>>(
        2, gi_dec, Wp_dec, dec_bhh, merged, nullptr, decA, TTGT,
        nullptr, nullptr, nullptr, nullptr, nullptr, nullptr, 0);

    // 6) logits GEMM + LSE partials (grid = 782*20)
    k_logits<<<NT * 20, 256, 0, stream>>>(decA, outWb, out_b, dout, pmax, psum);

    // 7) per-row logsumexp
    k_lse<<<MT, 256, 0, stream>>>(pmax, psum, lse);

    // 8) loss scalars
    k_loss<<<1, 256, 0, stream>>>(lse, target_tensor, dout);
}